// Round 2
// baseline (8279.277 us; speedup 1.0000x reference)
//
#include <hip/hip_runtime.h>
#include <math.h>

#define BN 2048
#define DN 8
#define NEGW -1e9f

static __device__ __forceinline__ float wave_reduce_max(float v){
  #pragma unroll
  for (int off = 32; off > 0; off >>= 1) v = fmaxf(v, __shfl_xor(v, off, 64));
  return v;
}
static __device__ __forceinline__ float wave_reduce_sum(float v){
  #pragma unroll
  for (int off = 32; off > 0; off >>= 1) v += __shfl_xor(v, off, 64);
  return v;
}

// Transpose inputs into per-dim columns, build masked y, counts, logw.
__global__ void setup_kernel(const float* __restrict__ pred, const float* __restrict__ targ,
                             float* __restrict__ xcol, float* __restrict__ ycol,
                             float* __restrict__ logw, float* __restrict__ counts){
  int d = blockIdx.x;          // 8 blocks
  int t = threadIdx.x;         // 256 threads
  int lane = t & 63, wave = t >> 6;
  float mk[BN/256];
  float c = 0.f;
  for (int k = 0; k < BN/256; k++){
    int i = t + k*256;
    float tv = targ[i*DN + d];
    bool m = !(tv != tv);      // !isnan
    mk[k] = m ? 1.f : 0.f;
    c += mk[k];
    ycol[d*BN + i] = m ? tv : 0.f;
    xcol[d*BN + i] = pred[i*DN + d];
  }
  __shared__ float sh[4];
  __shared__ float logn_sh;
  float cw = wave_reduce_sum(c);
  if (lane == 0) sh[wave] = cw;
  __syncthreads();
  if (t == 0){
    float tot = sh[0] + sh[1] + sh[2] + sh[3];
    counts[d] = tot;
    logn_sh = logf(fmaxf(tot, 1.f));
  }
  __syncthreads();
  float ln = logn_sh;
  for (int k = 0; k < BN/256; k++){
    int i = t + k*256;
    logw[d*BN + i] = (mk[k] > 0.f) ? -ln : NEGW;
  }
}

// One Sinkhorn phase: 4 softmins (f,g,a,b) for all 8 dims.
// mode 0 = init (h = logw, no damping)
// mode 1 = scan step (h = logw + dual/eps, damped 0.5*(old+new))
// mode 2 = final extrapolation (f,g full update; a,b damped)
//
// Row-constant shift trick: h[j] - (x_i - y_j)^2/(2 eps)
//   = (h[j] - y_j^2/(2 eps)) + (x_i/eps) * y_j - x_i^2/(2 eps)
// Everything kept in log2 domain so exp2f/log2f map to v_exp_f32/v_log_f32.
//
// Grid: 8 dims x 4 mats x 64 chunks of 32 rows = 2048 blocks x 4 waves
//     = 8192 waves = 100% of the 256-CU x 32-wave capacity.
// __launch_bounds__(256,8): 8 waves/EU -> VGPR capped at 64 (j-cache is
// exactly 64 regs; crossing 64 VGPRs would halve occupancy).
__global__ __launch_bounds__(256, 8) void sink_step(
      const float* __restrict__ xcol, const float* __restrict__ ycol,
      const float* __restrict__ logw,
      const float* __restrict__ dold, float* __restrict__ dnew,
      float eps, float inv_eps, int mode){
  const float L2E = 1.44269504088896340736f;
  const float LN2 = 0.69314718055994530942f;
  int bid   = blockIdx.x;
  int chunk = bid & 63;        // 64 row-chunks of 32 rows
  int mat   = (bid >> 6) & 3;  // 0:f 1:g 2:a 3:b
  int d     = bid >> 8;        // dim
  int lane  = threadIdx.x & 63;
  int wave  = threadIdx.x >> 6;

  const float* xb = xcol + d*BN;
  const float* yb = ycol + d*BN;
  const float* lw = logw + d*BN;
  const float* ri; const float* pj; int hsel;
  switch (mat){
    case 0:  ri = xb; pj = yb; hsel = 1; break;  // ft: rows x, pts y, dual g
    case 1:  ri = yb; pj = xb; hsel = 0; break;  // gt: rows y, pts x, dual f
    case 2:  ri = xb; pj = xb; hsel = 2; break;  // at
    default: ri = yb; pj = yb; hsel = 3; break;  // bt
  }
  const float* hd  = dold + (size_t)hsel*DN*BN + d*BN;
  const float* dmp = dold + (size_t)mat *DN*BN + d*BN;
  float*       op  = dnew + (size_t)mat *DN*BN + d*BN;

  const float c1 = L2E * inv_eps;          // log2-domain 1/eps
  const float c2 = 0.5f * inv_eps * L2E;   // log2-domain 1/(2 eps)

  // Cache this lane's j-slice (32 of 2048) in registers. (64 VGPRs)
  float yv[32], h2[32];
  #pragma unroll
  for (int k = 0; k < 32; k++){
    int j = lane + (k << 6);
    float y  = pj[j];
    float hv = lw[j];
    if (mode != 0) hv = fmaf(hd[j], inv_eps, hv);
    yv[k] = y;
    h2[k] = fmaf(-c2 * y, y, L2E * hv);
  }

  int row0 = chunk*32 + wave*8;
  float res = 0.f;
  #pragma unroll 1
  for (int r = 0; r < 8; r++){
    int i = row0 + r;
    float xi    = ri[i];                 // wave-uniform broadcast load
    float alpha = c1 * xi;
    float beta2 = c2 * xi * xi;
    float m = -INFINITY;
    #pragma unroll
    for (int k = 0; k < 32; k++) m = fmaxf(m, fmaf(alpha, yv[k], h2[k]));
    m = wave_reduce_max(m);
    float s = 0.f;
    #pragma unroll
    for (int k = 0; k < 32; k++) s += exp2f(fmaf(alpha, yv[k], h2[k]) - m);
    s = wave_reduce_sum(s);
    float lse2 = (m + log2f(s)) - beta2;     // log2-domain LSE (shift restored)
    float tn = -eps * (LN2 * lse2);
    float outv;
    if (mode == 1 || (mode == 2 && mat >= 2)) outv = 0.5f * (dmp[i] + tn);
    else                                      outv = tn;
    if (lane == r) res = outv;
  }
  if (lane < 8) op[row0 + lane] = res;
}

__global__ void reduce_kernel(const float* __restrict__ dual, const float* __restrict__ logw,
                              const float* __restrict__ counts, float* __restrict__ out){
  int d = blockIdx.x;
  int t = threadIdx.x;
  int lane = t & 63, wave = t >> 6;
  float acc = 0.f;
  for (int k = 0; k < BN/256; k++){
    int i = t + k*256;
    float w  = expf(logw[d*BN + i]);   // exp(-1e9) -> 0, else 1/n
    float fv = dual[0*DN*BN + d*BN + i];
    float gv = dual[1*DN*BN + d*BN + i];
    float av = dual[2*DN*BN + d*BN + i];
    float bv = dual[3*DN*BN + d*BN + i];
    acc += w * ((fv - av) + (gv - bv));
  }
  __shared__ float sh[4];
  float aw = wave_reduce_sum(acc);
  if (lane == 0) sh[wave] = aw;
  __syncthreads();
  if (t == 0){
    float tot = sh[0] + sh[1] + sh[2] + sh[3];
    out[1 + d] = (counts[d] > 1.5f) ? tot : 0.f;
  }
}

__global__ void total_kernel(float* __restrict__ out){
  if (threadIdx.x == 0 && blockIdx.x == 0){
    float s = 0.f;
    for (int d = 0; d < DN; d++) s += out[1 + d];
    out[0] = s / (float)DN;
  }
}

extern "C" void kernel_launch(void* const* d_in, const int* in_sizes, int n_in,
                              void* d_out, int out_size, void* d_ws, size_t ws_size,
                              hipStream_t stream){
  const float* pred = (const float*)d_in[0];
  const float* targ = (const float*)d_in[1];
  float* out = (float*)d_out;
  float* ws  = (float*)d_ws;

  float* xcol   = ws;
  float* ycol   = ws + (size_t)DN*BN;
  float* logw   = ws + (size_t)2*DN*BN;
  float* counts = ws + (size_t)3*DN*BN;
  float* buf0   = ws + (size_t)3*DN*BN + 64;
  float* buf1   = buf0 + (size_t)4*DN*BN;

  // eps schedule (matches geomloss: diameter^p -> blur^p geometric, ratio scaling^p)
  float eps_list[64]; int n = 0;
  {
    const double P = 2.0, DIAM = 8.0, BLUR = 0.05, SC = 0.9;
    double ls = P*log(DIAM), le = P*log(BLUR), st = P*log(SC);
    eps_list[n++] = (float)pow(DIAM, P);                 // 64
    int cnt = (int)ceil((le - ls)/st);                   // 49
    for (int k = 0; k < cnt; k++) eps_list[n++] = (float)exp(ls + st*(double)k);
    eps_list[n++] = (float)(BLUR*BLUR);                  // 0.0025
  }

  setup_kernel<<<DN, 256, 0, stream>>>(pred, targ, xcol, ycol, logw, counts);

  dim3 grid(DN*4*64), blk(256);
  float* cur = buf0; float* nxt = buf1;
  {
    float e = eps_list[0];
    sink_step<<<grid, blk, 0, stream>>>(xcol, ycol, logw, cur, cur, e, 1.f/e, 0);
  }
  for (int k = 0; k < n; k++){
    float e = eps_list[k];
    sink_step<<<grid, blk, 0, stream>>>(xcol, ycol, logw, cur, nxt, e, 1.f/e, 1);
    float* tmp = cur; cur = nxt; nxt = tmp;
  }
  {
    float e = eps_list[n-1];
    sink_step<<<grid, blk, 0, stream>>>(xcol, ycol, logw, cur, nxt, e, 1.f/e, 2);
    float* tmp = cur; cur = nxt; nxt = tmp;
  }
  reduce_kernel<<<DN, 256, 0, stream>>>(cur, logw, counts, out);
  total_kernel<<<1, 64, 0, stream>>>(out);
}

// Round 3
// 2866.537 us; speedup vs baseline: 2.8883x; 2.8883x over previous
//
#include <hip/hip_runtime.h>
#include <math.h>

#define BN 2048
#define DN 8
#define NEGW -1e9f

static __device__ __forceinline__ float wave_reduce_max(float v){
  #pragma unroll
  for (int off = 32; off > 0; off >>= 1) v = fmaxf(v, __shfl_xor(v, off, 64));
  return v;
}
static __device__ __forceinline__ float wave_reduce_sum(float v){
  #pragma unroll
  for (int off = 32; off > 0; off >>= 1) v += __shfl_xor(v, off, 64);
  return v;
}

// Transpose inputs into per-dim columns, build masked y, counts, logw.
__global__ void setup_kernel(const float* __restrict__ pred, const float* __restrict__ targ,
                             float* __restrict__ xcol, float* __restrict__ ycol,
                             float* __restrict__ logw, float* __restrict__ counts){
  int d = blockIdx.x;          // 8 blocks
  int t = threadIdx.x;         // 256 threads
  int lane = t & 63, wave = t >> 6;
  float mk[BN/256];
  float c = 0.f;
  for (int k = 0; k < BN/256; k++){
    int i = t + k*256;
    float tv = targ[i*DN + d];
    bool m = !(tv != tv);      // !isnan
    mk[k] = m ? 1.f : 0.f;
    c += mk[k];
    ycol[d*BN + i] = m ? tv : 0.f;
    xcol[d*BN + i] = pred[i*DN + d];
  }
  __shared__ float sh[4];
  __shared__ float logn_sh;
  float cw = wave_reduce_sum(c);
  if (lane == 0) sh[wave] = cw;
  __syncthreads();
  if (t == 0){
    float tot = sh[0] + sh[1] + sh[2] + sh[3];
    counts[d] = tot;
    logn_sh = logf(fmaxf(tot, 1.f));
  }
  __syncthreads();
  float ln = logn_sh;
  for (int k = 0; k < BN/256; k++){
    int i = t + k*256;
    logw[d*BN + i] = (mk[k] > 0.f) ? -ln : NEGW;
  }
}

// One Sinkhorn phase: 4 softmins (f,g,a,b) for all 8 dims.
// mode 0 = init (h = logw, no damping)
// mode 1 = scan step (h = logw + dual/eps, damped 0.5*(old+new))
// mode 2 = final extrapolation (f,g full update; a,b damped)
//
// Row-constant shift trick: h[j] - (x_i - y_j)^2/(2 eps)
//   = (h[j] - y_j^2/(2 eps)) + (x_i/eps) * y_j - x_i^2/(2 eps)
// Everything kept in log2 domain so exp2f/log2f map to v_exp_f32/v_log_f32.
//
// Grid: 8 dims x 4 mats x 64 chunks of 32 rows = 2048 blocks x 4 waves
//     = 8192 waves = 100% of the 256-CU x 32-wave capacity.
// NOTE (round-2 post-mortem): do NOT add a min-waves launch_bounds here.
// __launch_bounds__(256,8) forced VGPR=32 -> the 64-reg j-cache spilled to
// scratch -> FETCH_SIZE 1.8MB -> 452MB, 3x slowdown. Natural allocation is
// ~60 VGPR which already permits 8 waves/SIMD.
__global__ __launch_bounds__(256) void sink_step(
      const float* __restrict__ xcol, const float* __restrict__ ycol,
      const float* __restrict__ logw,
      const float* __restrict__ dold, float* __restrict__ dnew,
      float eps, float inv_eps, int mode){
  const float L2E = 1.44269504088896340736f;
  const float LN2 = 0.69314718055994530942f;
  int bid   = blockIdx.x;
  int chunk = bid & 63;        // 64 row-chunks of 32 rows
  int mat   = (bid >> 6) & 3;  // 0:f 1:g 2:a 3:b
  int d     = bid >> 8;        // dim
  int lane  = threadIdx.x & 63;
  int wave  = threadIdx.x >> 6;

  const float* xb = xcol + d*BN;
  const float* yb = ycol + d*BN;
  const float* lw = logw + d*BN;
  const float* ri; const float* pj; int hsel;
  switch (mat){
    case 0:  ri = xb; pj = yb; hsel = 1; break;  // ft: rows x, pts y, dual g
    case 1:  ri = yb; pj = xb; hsel = 0; break;  // gt: rows y, pts x, dual f
    case 2:  ri = xb; pj = xb; hsel = 2; break;  // at
    default: ri = yb; pj = yb; hsel = 3; break;  // bt
  }
  const float* hd  = dold + (size_t)hsel*DN*BN + d*BN;
  const float* dmp = dold + (size_t)mat *DN*BN + d*BN;
  float*       op  = dnew + (size_t)mat *DN*BN + d*BN;

  const float c1 = L2E * inv_eps;          // log2-domain 1/eps
  const float c2 = 0.5f * inv_eps * L2E;   // log2-domain 1/(2 eps)

  // Cache this lane's j-slice (32 of 2048) in registers. (64 VGPRs)
  float yv[32], h2[32];
  #pragma unroll
  for (int k = 0; k < 32; k++){
    int j = lane + (k << 6);
    float y  = pj[j];
    float hv = lw[j];
    if (mode != 0) hv = fmaf(hd[j], inv_eps, hv);
    yv[k] = y;
    h2[k] = fmaf(-c2 * y, y, L2E * hv);
  }

  int row0 = chunk*32 + wave*8;
  float res = 0.f;
  #pragma unroll 1
  for (int r = 0; r < 8; r++){
    int i = row0 + r;
    float xi    = ri[i];                 // wave-uniform broadcast load
    float alpha = c1 * xi;
    float beta2 = c2 * xi * xi;
    float m = -INFINITY;
    #pragma unroll
    for (int k = 0; k < 32; k++) m = fmaxf(m, fmaf(alpha, yv[k], h2[k]));
    m = wave_reduce_max(m);
    float s = 0.f;
    #pragma unroll
    for (int k = 0; k < 32; k++) s += exp2f(fmaf(alpha, yv[k], h2[k]) - m);
    s = wave_reduce_sum(s);
    float lse2 = (m + log2f(s)) - beta2;     // log2-domain LSE (shift restored)
    float tn = -eps * (LN2 * lse2);
    float outv;
    if (mode == 1 || (mode == 2 && mat >= 2)) outv = 0.5f * (dmp[i] + tn);
    else                                      outv = tn;
    if (lane == r) res = outv;
  }
  if (lane < 8) op[row0 + lane] = res;
}

__global__ void reduce_kernel(const float* __restrict__ dual, const float* __restrict__ logw,
                              const float* __restrict__ counts, float* __restrict__ out){
  int d = blockIdx.x;
  int t = threadIdx.x;
  int lane = t & 63, wave = t >> 6;
  float acc = 0.f;
  for (int k = 0; k < BN/256; k++){
    int i = t + k*256;
    float w  = expf(logw[d*BN + i]);   // exp(-1e9) -> 0, else 1/n
    float fv = dual[0*DN*BN + d*BN + i];
    float gv = dual[1*DN*BN + d*BN + i];
    float av = dual[2*DN*BN + d*BN + i];
    float bv = dual[3*DN*BN + d*BN + i];
    acc += w * ((fv - av) + (gv - bv));
  }
  __shared__ float sh[4];
  float aw = wave_reduce_sum(acc);
  if (lane == 0) sh[wave] = aw;
  __syncthreads();
  if (t == 0){
    float tot = sh[0] + sh[1] + sh[2] + sh[3];
    out[1 + d] = (counts[d] > 1.5f) ? tot : 0.f;
  }
}

__global__ void total_kernel(float* __restrict__ out){
  if (threadIdx.x == 0 && blockIdx.x == 0){
    float s = 0.f;
    for (int d = 0; d < DN; d++) s += out[1 + d];
    out[0] = s / (float)DN;
  }
}

extern "C" void kernel_launch(void* const* d_in, const int* in_sizes, int n_in,
                              void* d_out, int out_size, void* d_ws, size_t ws_size,
                              hipStream_t stream){
  const float* pred = (const float*)d_in[0];
  const float* targ = (const float*)d_in[1];
  float* out = (float*)d_out;
  float* ws  = (float*)d_ws;

  float* xcol   = ws;
  float* ycol   = ws + (size_t)DN*BN;
  float* logw   = ws + (size_t)2*DN*BN;
  float* counts = ws + (size_t)3*DN*BN;
  float* buf0   = ws + (size_t)3*DN*BN + 64;
  float* buf1   = buf0 + (size_t)4*DN*BN;

  // eps schedule (matches geomloss: diameter^p -> blur^p geometric, ratio scaling^p)
  float eps_list[64]; int n = 0;
  {
    const double P = 2.0, DIAM = 8.0, BLUR = 0.05, SC = 0.9;
    double ls = P*log(DIAM), le = P*log(BLUR), st = P*log(SC);
    eps_list[n++] = (float)pow(DIAM, P);                 // 64
    int cnt = (int)ceil((le - ls)/st);                   // 49
    for (int k = 0; k < cnt; k++) eps_list[n++] = (float)exp(ls + st*(double)k);
    eps_list[n++] = (float)(BLUR*BLUR);                  // 0.0025
  }

  setup_kernel<<<DN, 256, 0, stream>>>(pred, targ, xcol, ycol, logw, counts);

  dim3 grid(DN*4*64), blk(256);
  float* cur = buf0; float* nxt = buf1;
  {
    float e = eps_list[0];
    sink_step<<<grid, blk, 0, stream>>>(xcol, ycol, logw, cur, cur, e, 1.f/e, 0);
  }
  for (int k = 0; k < n; k++){
    float e = eps_list[k];
    sink_step<<<grid, blk, 0, stream>>>(xcol, ycol, logw, cur, nxt, e, 1.f/e, 1);
    float* tmp = cur; cur = nxt; nxt = tmp;
  }
  {
    float e = eps_list[n-1];
    sink_step<<<grid, blk, 0, stream>>>(xcol, ycol, logw, cur, nxt, e, 1.f/e, 2);
    float* tmp = cur; cur = nxt; nxt = tmp;
  }
  reduce_kernel<<<DN, 256, 0, stream>>>(cur, logw, counts, out);
  total_kernel<<<1, 64, 0, stream>>>(out);
}

// Round 4
// 1338.181 us; speedup vs baseline: 6.1870x; 2.1421x over previous
//
#include <hip/hip_runtime.h>
#include <math.h>

#define BN 2048
#define DN 8
#define NEGW -1e9f
#define TPB 512          // threads per block (8 waves)
#define RPB 128          // rows per block (one row per lane-thread)
#define JSPLIT 4         // j-range split; each thread reduces 512 js
#define JPT (BN/JSPLIT)

static __device__ __forceinline__ float wave_reduce_sum(float v){
  #pragma unroll
  for (int off = 32; off > 0; off >>= 1) v += __shfl_xor(v, off, 64);
  return v;
}

// Transpose inputs into per-dim columns, build masked y, counts, logw.
__global__ void setup_kernel(const float* __restrict__ pred, const float* __restrict__ targ,
                             float* __restrict__ xcol, float* __restrict__ ycol,
                             float* __restrict__ logw, float* __restrict__ counts){
  int d = blockIdx.x;          // 8 blocks
  int t = threadIdx.x;         // 256 threads
  int lane = t & 63, wave = t >> 6;
  float mk[BN/256];
  float c = 0.f;
  for (int k = 0; k < BN/256; k++){
    int i = t + k*256;
    float tv = targ[i*DN + d];
    bool m = !(tv != tv);      // !isnan
    mk[k] = m ? 1.f : 0.f;
    c += mk[k];
    ycol[d*BN + i] = m ? tv : 0.f;
    xcol[d*BN + i] = pred[i*DN + d];
  }
  __shared__ float sh[4];
  __shared__ float logn_sh;
  float cw = wave_reduce_sum(c);
  if (lane == 0) sh[wave] = cw;
  __syncthreads();
  if (t == 0){
    float tot = sh[0] + sh[1] + sh[2] + sh[3];
    counts[d] = tot;
    logn_sh = logf(fmaxf(tot, 1.f));
  }
  __syncthreads();
  float ln = logn_sh;
  for (int k = 0; k < BN/256; k++){
    int i = t + k*256;
    logw[d*BN + i] = (mk[k] > 0.f) ? -ln : NEGW;
  }
}

// One Sinkhorn phase, row-per-lane decomposition.
// mode 0 = init (h = logw, no damping)
// mode 1 = scan step (h = logw + dual/eps, damped 0.5*(old+new))
// mode 2 = final extrapolation (f,g full update; a,b damped)
//
// Shift trick: h[j] - (x_i-y_j)^2/(2eps) = (h[j]-y_j^2/2eps) + (x_i/eps)y_j - x_i^2/2eps
// (y_j, h2_j) staged once per block in LDS; every lane owns ONE row and reduces
// a 512-j sub-range with 4 independent accumulators -> no cross-lane shuffles,
// no long dependent chains. LDS reads are wave-uniform broadcasts (free).
// 4-way j-chunk combine via tiny LDS arrays (stride-1, conflict-free).
__global__ __launch_bounds__(TPB) void sink_step(
      const float* __restrict__ xcol, const float* __restrict__ ycol,
      const float* __restrict__ logw,
      const float* __restrict__ dold, float* __restrict__ dnew,
      float eps, float inv_eps, int mode){
  const float L2E = 1.44269504088896340736f;
  const float LN2 = 0.69314718055994530942f;
  __shared__ float4 pair4[BN/2];          // (y0,h2_0,y1,h2_1) per slot, 16 KB
  __shared__ float pm[JSPLIT][RPB];
  __shared__ float ps[JSPLIT][RPB];

  int bid = blockIdx.x;
  int rc  = bid & 15;          // 16 row-chunks of 128 rows
  int mat = (bid >> 4) & 3;    // 0:f 1:g 2:a 3:b
  int d   = bid >> 6;          // dim
  int t   = threadIdx.x;
  int r   = t & (RPB-1);       // row within chunk (lane-consecutive)
  int jc  = t >> 7;            // j-chunk 0..3 (wave-uniform)

  const float* xb = xcol + d*BN;
  const float* yb = ycol + d*BN;
  const float* lw = logw + d*BN;
  const float* ri; const float* pj; int hsel;
  switch (mat){
    case 0:  ri = xb; pj = yb; hsel = 1; break;  // ft: rows x, pts y, dual g
    case 1:  ri = yb; pj = xb; hsel = 0; break;  // gt: rows y, pts x, dual f
    case 2:  ri = xb; pj = xb; hsel = 2; break;  // at
    default: ri = yb; pj = yb; hsel = 3; break;  // bt
  }
  const float* hd  = dold + (size_t)hsel*DN*BN + d*BN;
  const float* dmp = dold + (size_t)mat *DN*BN + d*BN;
  float*       op  = dnew + (size_t)mat *DN*BN + d*BN;

  const float c1 = L2E * inv_eps;          // log2-domain 1/eps
  const float c2 = 0.5f * inv_eps * L2E;   // log2-domain 1/(2 eps)

  // ---- stage (y, h2) for all 2048 j into LDS (coalesced b64 loads) ----
  const float2* pj2 = (const float2*)pj;
  const float2* lw2 = (const float2*)lw;
  const float2* hd2 = (const float2*)hd;
  #pragma unroll
  for (int k = 0; k < BN/2/TPB; k++){      // 2 iters
    int idx = t + k*TPB;
    float2 y2 = pj2[idx];
    float2 l2 = lw2[idx];
    float h0 = l2.x, h1 = l2.y;
    if (mode != 0){
      float2 dd = hd2[idx];
      h0 = fmaf(dd.x, inv_eps, h0);
      h1 = fmaf(dd.y, inv_eps, h1);
    }
    pair4[idx] = make_float4(y2.x, fmaf(-c2*y2.x, y2.x, L2E*h0),
                             y2.y, fmaf(-c2*y2.y, y2.y, L2E*h1));
  }

  int row = rc*RPB + r;
  float xi    = ri[row];                   // coalesced per-lane row load
  float alpha = c1 * xi;
  float beta2 = c2 * xi * xi;
  __syncthreads();

  // ---- pass 1: per-row max over this thread's 512-j sub-range ----
  int q0 = jc * (JPT/2);                   // float4 slot base
  float m0=-INFINITY, m1=-INFINITY, m2=-INFINITY, m3=-INFINITY;
  #pragma unroll 4
  for (int q = 0; q < JPT/2; q += 2){
    float4 A = pair4[q0+q];
    float4 B = pair4[q0+q+1];
    m0 = fmaxf(m0, fmaf(alpha, A.x, A.y));
    m1 = fmaxf(m1, fmaf(alpha, A.z, A.w));
    m2 = fmaxf(m2, fmaf(alpha, B.x, B.y));
    m3 = fmaxf(m3, fmaf(alpha, B.z, B.w));
  }
  float m = fmaxf(fmaxf(m0, m1), fmaxf(m2, m3));
  pm[jc][r] = m;
  __syncthreads();
  m = fmaxf(fmaxf(pm[0][r], pm[1][r]), fmaxf(pm[2][r], pm[3][r]));

  // ---- pass 2: sum of exp2 with combined max ----
  float s0=0.f, s1=0.f, s2=0.f, s3=0.f;
  #pragma unroll 4
  for (int q = 0; q < JPT/2; q += 2){
    float4 A = pair4[q0+q];
    float4 B = pair4[q0+q+1];
    s0 += __builtin_amdgcn_exp2f(fmaf(alpha, A.x, A.y) - m);
    s1 += __builtin_amdgcn_exp2f(fmaf(alpha, A.z, A.w) - m);
    s2 += __builtin_amdgcn_exp2f(fmaf(alpha, B.x, B.y) - m);
    s3 += __builtin_amdgcn_exp2f(fmaf(alpha, B.z, B.w) - m);
  }
  ps[jc][r] = (s0+s1) + (s2+s3);
  __syncthreads();

  if (t < RPB){
    float s = (ps[0][r] + ps[1][r]) + (ps[2][r] + ps[3][r]);
    float lse2 = (m + __builtin_amdgcn_logf(s)) - beta2;  // log2-domain LSE
    float tn = -eps * (LN2 * lse2);
    float outv;
    if (mode == 1 || (mode == 2 && mat >= 2)) outv = 0.5f * (dmp[row] + tn);
    else                                      outv = tn;
    op[row] = outv;
  }
}

__global__ void reduce_kernel(const float* __restrict__ dual, const float* __restrict__ logw,
                              const float* __restrict__ counts, float* __restrict__ out){
  int d = blockIdx.x;
  int t = threadIdx.x;
  int lane = t & 63, wave = t >> 6;
  float acc = 0.f;
  for (int k = 0; k < BN/256; k++){
    int i = t + k*256;
    float w  = expf(logw[d*BN + i]);   // exp(-1e9) -> 0, else 1/n
    float fv = dual[0*DN*BN + d*BN + i];
    float gv = dual[1*DN*BN + d*BN + i];
    float av = dual[2*DN*BN + d*BN + i];
    float bv = dual[3*DN*BN + d*BN + i];
    acc += w * ((fv - av) + (gv - bv));
  }
  __shared__ float sh[4];
  float aw = wave_reduce_sum(acc);
  if (lane == 0) sh[wave] = aw;
  __syncthreads();
  if (t == 0){
    float tot = sh[0] + sh[1] + sh[2] + sh[3];
    out[1 + d] = (counts[d] > 1.5f) ? tot : 0.f;
  }
}

__global__ void total_kernel(float* __restrict__ out){
  if (threadIdx.x == 0 && blockIdx.x == 0){
    float s = 0.f;
    for (int d = 0; d < DN; d++) s += out[1 + d];
    out[0] = s / (float)DN;
  }
}

extern "C" void kernel_launch(void* const* d_in, const int* in_sizes, int n_in,
                              void* d_out, int out_size, void* d_ws, size_t ws_size,
                              hipStream_t stream){
  const float* pred = (const float*)d_in[0];
  const float* targ = (const float*)d_in[1];
  float* out = (float*)d_out;
  float* ws  = (float*)d_ws;

  float* xcol   = ws;
  float* ycol   = ws + (size_t)DN*BN;
  float* logw   = ws + (size_t)2*DN*BN;
  float* counts = ws + (size_t)3*DN*BN;
  float* buf0   = ws + (size_t)3*DN*BN + 64;
  float* buf1   = buf0 + (size_t)4*DN*BN;

  // eps schedule (matches geomloss: diameter^p -> blur^p geometric, ratio scaling^p)
  float eps_list[64]; int n = 0;
  {
    const double P = 2.0, DIAM = 8.0, BLUR = 0.05, SC = 0.9;
    double ls = P*log(DIAM), le = P*log(BLUR), st = P*log(SC);
    eps_list[n++] = (float)pow(DIAM, P);                 // 64
    int cnt = (int)ceil((le - ls)/st);                   // 49
    for (int k = 0; k < cnt; k++) eps_list[n++] = (float)exp(ls + st*(double)k);
    eps_list[n++] = (float)(BLUR*BLUR);                  // 0.0025
  }

  setup_kernel<<<DN, 256, 0, stream>>>(pred, targ, xcol, ycol, logw, counts);

  dim3 grid(DN*4*16), blk(TPB);
  float* cur = buf0; float* nxt = buf1;
  {
    float e = eps_list[0];
    sink_step<<<grid, blk, 0, stream>>>(xcol, ycol, logw, cur, cur, e, 1.f/e, 0);
  }
  for (int k = 0; k < n; k++){
    float e = eps_list[k];
    sink_step<<<grid, blk, 0, stream>>>(xcol, ycol, logw, cur, nxt, e, 1.f/e, 1);
    float* tmp = cur; cur = nxt; nxt = tmp;
  }
  {
    float e = eps_list[n-1];
    sink_step<<<grid, blk, 0, stream>>>(xcol, ycol, logw, cur, nxt, e, 1.f/e, 2);
    float* tmp = cur; cur = nxt; nxt = tmp;
  }
  reduce_kernel<<<DN, 256, 0, stream>>>(cur, logw, counts, out);
  total_kernel<<<1, 64, 0, stream>>>(out);
}

// Round 5
// 1205.013 us; speedup vs baseline: 6.8707x; 1.1105x over previous
//
#include <hip/hip_runtime.h>
#include <math.h>

#define BN 2048
#define DN 8
#define NEGW -1e9f
#define TPB 256          // threads per block (4 waves)
#define RPB 64           // rows per block (each thread owns 2 rows)
#define JSPLIT 8         // j-chunks; jc = t>>5 (per half-wave -> 2-way LDS broadcast, free)
#define SLOTS (BN/2)     // float4 slots (2 j per slot)
#define SPC (SLOTS/JSPLIT) // 128 slots = 256 j per chunk

static __device__ __forceinline__ float wave_reduce_sum(float v){
  #pragma unroll
  for (int off = 32; off > 0; off >>= 1) v += __shfl_xor(v, off, 64);
  return v;
}

// Transpose inputs into per-dim columns, build masked y, counts, logw.
__global__ void setup_kernel(const float* __restrict__ pred, const float* __restrict__ targ,
                             float* __restrict__ xcol, float* __restrict__ ycol,
                             float* __restrict__ logw, float* __restrict__ counts){
  int d = blockIdx.x;          // 8 blocks
  int t = threadIdx.x;         // 256 threads
  int lane = t & 63, wave = t >> 6;
  float mk[BN/256];
  float c = 0.f;
  for (int k = 0; k < BN/256; k++){
    int i = t + k*256;
    float tv = targ[i*DN + d];
    bool m = !(tv != tv);      // !isnan
    mk[k] = m ? 1.f : 0.f;
    c += mk[k];
    ycol[d*BN + i] = m ? tv : 0.f;
    xcol[d*BN + i] = pred[i*DN + d];
  }
  __shared__ float sh[4];
  __shared__ float logn_sh;
  float cw = wave_reduce_sum(c);
  if (lane == 0) sh[wave] = cw;
  __syncthreads();
  if (t == 0){
    float tot = sh[0] + sh[1] + sh[2] + sh[3];
    counts[d] = tot;
    logn_sh = logf(fmaxf(tot, 1.f));
  }
  __syncthreads();
  float ln = logn_sh;
  for (int k = 0; k < BN/256; k++){
    int i = t + k*256;
    logw[d*BN + i] = (mk[k] > 0.f) ? -ln : NEGW;
  }
}

// One Sinkhorn phase, row-per-lane with 2 rows/thread (LDS traffic amortized).
// mode 0 = init; mode 1 = damped scan step; mode 2 = final extrapolation.
// Shift trick: h[j] - (x_i-y_j)^2/(2eps) = (h[j]-y_j^2/2eps) + (x_i/eps)y_j - x_i^2/2eps
// (y_j,h2_j) staged in LDS once per block; each thread reduces a 256-j chunk
// for TWO rows -> each float4 LDS read feeds 4 fma (2 j x 2 rows). No shuffles.
__global__ __launch_bounds__(TPB) void sink_step(
      const float* __restrict__ xcol, const float* __restrict__ ycol,
      const float* __restrict__ logw,
      const float* __restrict__ dold, float* __restrict__ dnew,
      float eps, float inv_eps, int mode){
  const float L2E = 1.44269504088896340736f;
  const float LN2 = 0.69314718055994530942f;
  __shared__ float4 pair4[SLOTS];         // 16 KB: (y0,h2_0,y1,h2_1)
  __shared__ float pm[JSPLIT][RPB];       // 2 KB
  __shared__ float ps[JSPLIT][RPB];       // 2 KB

  int bid = blockIdx.x;
  int rc  = bid & 31;          // 32 row-chunks of 64 rows
  int mat = (bid >> 5) & 3;    // 0:f 1:g 2:a 3:b
  int d   = bid >> 7;          // dim
  int t   = threadIdx.x;
  int rs  = t & 31;            // row-slot: rows rs and rs+32
  int jc  = t >> 5;            // j-chunk 0..7 (uniform per half-wave)

  const float* xb = xcol + d*BN;
  const float* yb = ycol + d*BN;
  const float* lw = logw + d*BN;
  const float* ri; const float* pj; int hsel;
  switch (mat){
    case 0:  ri = xb; pj = yb; hsel = 1; break;  // ft: rows x, pts y, dual g
    case 1:  ri = yb; pj = xb; hsel = 0; break;  // gt: rows y, pts x, dual f
    case 2:  ri = xb; pj = xb; hsel = 2; break;  // at
    default: ri = yb; pj = yb; hsel = 3; break;  // bt
  }
  const float* hd  = dold + (size_t)hsel*DN*BN + d*BN;
  const float* dmp = dold + (size_t)mat *DN*BN + d*BN;
  float*       op  = dnew + (size_t)mat *DN*BN + d*BN;

  const float c1 = L2E * inv_eps;          // log2-domain 1/eps
  const float c2 = 0.5f * inv_eps * L2E;   // log2-domain 1/(2 eps)

  // ---- stage (y, h2) for all 2048 j into LDS ----
  const float2* pj2 = (const float2*)pj;
  const float2* lw2 = (const float2*)lw;
  const float2* hd2 = (const float2*)hd;
  #pragma unroll
  for (int k = 0; k < BN/2/TPB; k++){      // 4 iters
    int idx = t + k*TPB;
    float2 y2 = pj2[idx];
    float2 l2 = lw2[idx];
    float h0 = l2.x, h1 = l2.y;
    if (mode != 0){
      float2 dd = hd2[idx];
      h0 = fmaf(dd.x, inv_eps, h0);
      h1 = fmaf(dd.y, inv_eps, h1);
    }
    pair4[idx] = make_float4(y2.x, fmaf(-c2*y2.x, y2.x, L2E*h0),
                             y2.y, fmaf(-c2*y2.y, y2.y, L2E*h1));
  }

  int row0 = rc*RPB + rs;
  int row1 = row0 + 32;
  float xi0 = ri[row0], xi1 = ri[row1];
  float alpha0 = c1 * xi0, beta0 = c2 * xi0 * xi0;
  float alpha1 = c1 * xi1, beta1 = c2 * xi1 * xi1;
  __syncthreads();

  // ---- pass 1: per-row max over this thread's 256-j chunk, 2 rows ----
  int q0 = jc * SPC;
  float m00=-INFINITY, m01=-INFINITY, m10=-INFINITY, m11=-INFINITY;
  #pragma unroll 4
  for (int q = 0; q < SPC; q += 2){
    float4 A = pair4[q0+q];
    float4 B = pair4[q0+q+1];
    m00 = fmaxf(m00, fmaf(alpha0, A.x, A.y));
    m01 = fmaxf(m01, fmaf(alpha0, A.z, A.w));
    m10 = fmaxf(m10, fmaf(alpha1, A.x, A.y));
    m11 = fmaxf(m11, fmaf(alpha1, A.z, A.w));
    m00 = fmaxf(m00, fmaf(alpha0, B.x, B.y));
    m01 = fmaxf(m01, fmaf(alpha0, B.z, B.w));
    m10 = fmaxf(m10, fmaf(alpha1, B.x, B.y));
    m11 = fmaxf(m11, fmaf(alpha1, B.z, B.w));
  }
  pm[jc][rs]      = fmaxf(m00, m01);
  pm[jc][rs+32]   = fmaxf(m10, m11);
  __syncthreads();
  float m0 = -INFINITY, m1 = -INFINITY;
  #pragma unroll
  for (int k = 0; k < JSPLIT; k++){
    m0 = fmaxf(m0, pm[k][rs]);
    m1 = fmaxf(m1, pm[k][rs+32]);
  }

  // ---- pass 2: sum of exp2 with combined max ----
  float s00=0.f, s01=0.f, s10=0.f, s11=0.f;
  #pragma unroll 4
  for (int q = 0; q < SPC; q += 2){
    float4 A = pair4[q0+q];
    float4 B = pair4[q0+q+1];
    s00 += __builtin_amdgcn_exp2f(fmaf(alpha0, A.x, A.y) - m0);
    s01 += __builtin_amdgcn_exp2f(fmaf(alpha0, A.z, A.w) - m0);
    s10 += __builtin_amdgcn_exp2f(fmaf(alpha1, A.x, A.y) - m1);
    s11 += __builtin_amdgcn_exp2f(fmaf(alpha1, A.z, A.w) - m1);
    s00 += __builtin_amdgcn_exp2f(fmaf(alpha0, B.x, B.y) - m0);
    s01 += __builtin_amdgcn_exp2f(fmaf(alpha0, B.z, B.w) - m0);
    s10 += __builtin_amdgcn_exp2f(fmaf(alpha1, B.x, B.y) - m1);
    s11 += __builtin_amdgcn_exp2f(fmaf(alpha1, B.z, B.w) - m1);
  }
  ps[jc][rs]    = (s00+s01);
  ps[jc][rs+32] = (s10+s11);
  __syncthreads();

  if (t < RPB){
    int row = rc*RPB + t;
    float s = 0.f;
    float m = -INFINITY;
    #pragma unroll
    for (int k = 0; k < JSPLIT; k++){
      s += ps[k][t];
      m  = fmaxf(m, pm[k][t]);
    }
    float beta = (t < 32) ? beta0 : beta1;
    float lse2 = (m + __builtin_amdgcn_logf(s)) - beta;   // log2-domain LSE
    float tn = -eps * (LN2 * lse2);
    float outv;
    if (mode == 1 || (mode == 2 && mat >= 2)) outv = 0.5f * (dmp[row] + tn);
    else                                      outv = tn;
    op[row] = outv;
  }
}

__global__ void reduce_kernel(const float* __restrict__ dual, const float* __restrict__ logw,
                              const float* __restrict__ counts, float* __restrict__ out){
  int d = blockIdx.x;
  int t = threadIdx.x;
  int lane = t & 63, wave = t >> 6;
  float acc = 0.f;
  for (int k = 0; k < BN/256; k++){
    int i = t + k*256;
    float w  = expf(logw[d*BN + i]);   // exp(-1e9) -> 0, else 1/n
    float fv = dual[0*DN*BN + d*BN + i];
    float gv = dual[1*DN*BN + d*BN + i];
    float av = dual[2*DN*BN + d*BN + i];
    float bv = dual[3*DN*BN + d*BN + i];
    acc += w * ((fv - av) + (gv - bv));
  }
  __shared__ float sh[4];
  float aw = wave_reduce_sum(acc);
  if (lane == 0) sh[wave] = aw;
  __syncthreads();
  if (t == 0){
    float tot = sh[0] + sh[1] + sh[2] + sh[3];
    out[1 + d] = (counts[d] > 1.5f) ? tot : 0.f;
  }
}

__global__ void total_kernel(float* __restrict__ out){
  if (threadIdx.x == 0 && blockIdx.x == 0){
    float s = 0.f;
    for (int d = 0; d < DN; d++) s += out[1 + d];
    out[0] = s / (float)DN;
  }
}

extern "C" void kernel_launch(void* const* d_in, const int* in_sizes, int n_in,
                              void* d_out, int out_size, void* d_ws, size_t ws_size,
                              hipStream_t stream){
  const float* pred = (const float*)d_in[0];
  const float* targ = (const float*)d_in[1];
  float* out = (float*)d_out;
  float* ws  = (float*)d_ws;

  float* xcol   = ws;
  float* ycol   = ws + (size_t)DN*BN;
  float* logw   = ws + (size_t)2*DN*BN;
  float* counts = ws + (size_t)3*DN*BN;
  float* buf0   = ws + (size_t)3*DN*BN + 64;
  float* buf1   = buf0 + (size_t)4*DN*BN;

  // eps schedule (matches geomloss: diameter^p -> blur^p geometric, ratio scaling^p)
  float eps_list[64]; int n = 0;
  {
    const double P = 2.0, DIAM = 8.0, BLUR = 0.05, SC = 0.9;
    double ls = P*log(DIAM), le = P*log(BLUR), st = P*log(SC);
    eps_list[n++] = (float)pow(DIAM, P);                 // 64
    int cnt = (int)ceil((le - ls)/st);                   // 49
    for (int k = 0; k < cnt; k++) eps_list[n++] = (float)exp(ls + st*(double)k);
    eps_list[n++] = (float)(BLUR*BLUR);                  // 0.0025
  }

  setup_kernel<<<DN, 256, 0, stream>>>(pred, targ, xcol, ycol, logw, counts);

  dim3 grid(DN*4*32), blk(TPB);
  float* cur = buf0; float* nxt = buf1;
  {
    float e = eps_list[0];
    sink_step<<<grid, blk, 0, stream>>>(xcol, ycol, logw, cur, cur, e, 1.f/e, 0);
  }
  for (int k = 0; k < n; k++){
    float e = eps_list[k];
    sink_step<<<grid, blk, 0, stream>>>(xcol, ycol, logw, cur, nxt, e, 1.f/e, 1);
    float* tmp = cur; cur = nxt; nxt = tmp;
  }
  {
    float e = eps_list[n-1];
    sink_step<<<grid, blk, 0, stream>>>(xcol, ycol, logw, cur, nxt, e, 1.f/e, 2);
    float* tmp = cur; cur = nxt; nxt = tmp;
  }
  reduce_kernel<<<DN, 256, 0, stream>>>(cur, logw, counts, out);
  total_kernel<<<1, 64, 0, stream>>>(out);
}

// Round 6
// 1197.062 us; speedup vs baseline: 6.9163x; 1.0066x over previous
//
#include <hip/hip_runtime.h>
#include <math.h>

#define BN 2048
#define DN 8
#define NEGW -1e9f
#define TPB 256          // threads per block (4 waves)
#define RPB 128          // rows per block (each thread owns 4 rows)
#define RS 32            // row-slots (t & 31); rows rs, rs+32, rs+64, rs+96
#define JSPLIT 8         // j-chunks; jc = t>>5
#define SLOTS (BN/2)     // float4 slots (2 j per slot)
#define SPC (SLOTS/JSPLIT) // 128 slots = 256 j per chunk

typedef float f2 __attribute__((ext_vector_type(2)));

static __device__ __forceinline__ float wave_reduce_sum(float v){
  #pragma unroll
  for (int off = 32; off > 0; off >>= 1) v += __shfl_xor(v, off, 64);
  return v;
}

// Transpose inputs into per-dim columns, build masked y, counts, logw.
__global__ void setup_kernel(const float* __restrict__ pred, const float* __restrict__ targ,
                             float* __restrict__ xcol, float* __restrict__ ycol,
                             float* __restrict__ logw, float* __restrict__ counts){
  int d = blockIdx.x;          // 8 blocks
  int t = threadIdx.x;         // 256 threads
  int lane = t & 63, wave = t >> 6;
  float mk[BN/256];
  float c = 0.f;
  for (int k = 0; k < BN/256; k++){
    int i = t + k*256;
    float tv = targ[i*DN + d];
    bool m = !(tv != tv);      // !isnan
    mk[k] = m ? 1.f : 0.f;
    c += mk[k];
    ycol[d*BN + i] = m ? tv : 0.f;
    xcol[d*BN + i] = pred[i*DN + d];
  }
  __shared__ float sh[4];
  __shared__ float logn_sh;
  float cw = wave_reduce_sum(c);
  if (lane == 0) sh[wave] = cw;
  __syncthreads();
  if (t == 0){
    float tot = sh[0] + sh[1] + sh[2] + sh[3];
    counts[d] = tot;
    logn_sh = logf(fmaxf(tot, 1.f));
  }
  __syncthreads();
  float ln = logn_sh;
  for (int k = 0; k < BN/256; k++){
    int i = t + k*256;
    logw[d*BN + i] = (mk[k] > 0.f) ? -ln : NEGW;
  }
}

// One Sinkhorn phase. Round-6 structure: 4 rows/thread (halves LDS insts,
// the round-5 binding pipe: 16 waves x 256 ds_read_b128 x 12cyc = 49K cyc/CU
// matched the 20.5us exactly) + packed f32 math via float2 elementwise
// builtins (v_pk_fma/pk_max/pk_add). LDS layout is PLANAR per float4:
// (y0,y1,h2_0,h2_1) so pk operands are contiguous register pairs.
__global__ __launch_bounds__(TPB) void sink_step(
      const float* __restrict__ xcol, const float* __restrict__ ycol,
      const float* __restrict__ logw,
      const float* __restrict__ dold, float* __restrict__ dnew,
      float eps, float inv_eps, int mode){
  const float L2E = 1.44269504088896340736f;
  const float LN2 = 0.69314718055994530942f;
  __shared__ float4 pair4[SLOTS];         // 16 KB planar: (y0,y1,h2_0,h2_1)
  __shared__ float pm[JSPLIT][RPB];       // 4 KB partial max
  __shared__ float ps[JSPLIT][RPB];       // 4 KB partial sum
  __shared__ float mmx[RPB];              // combined max per row

  int bid = blockIdx.x;
  int rc  = bid & 15;          // 16 row-chunks of 128 rows
  int mat = (bid >> 4) & 3;    // 0:f 1:g 2:a 3:b
  int d   = bid >> 6;          // dim
  int t   = threadIdx.x;
  int rs  = t & (RS-1);        // row-slot
  int jc  = t >> 5;            // j-chunk 0..7

  const float* xb = xcol + d*BN;
  const float* yb = ycol + d*BN;
  const float* lw = logw + d*BN;
  const float* ri; const float* pj; int hsel;
  switch (mat){
    case 0:  ri = xb; pj = yb; hsel = 1; break;  // ft: rows x, pts y, dual g
    case 1:  ri = yb; pj = xb; hsel = 0; break;  // gt: rows y, pts x, dual f
    case 2:  ri = xb; pj = xb; hsel = 2; break;  // at
    default: ri = yb; pj = yb; hsel = 3; break;  // bt
  }
  const float* hd  = dold + (size_t)hsel*DN*BN + d*BN;
  const float* dmp = dold + (size_t)mat *DN*BN + d*BN;
  float*       op  = dnew + (size_t)mat *DN*BN + d*BN;

  const float c1 = L2E * inv_eps;          // log2-domain 1/eps
  const float c2 = 0.5f * inv_eps * L2E;   // log2-domain 1/(2 eps)

  // ---- stage (y,y,h2,h2) planar for all 2048 j into LDS ----
  const float2* pj2 = (const float2*)pj;
  const float2* lw2 = (const float2*)lw;
  const float2* hd2 = (const float2*)hd;
  #pragma unroll
  for (int k = 0; k < SLOTS/TPB; k++){     // 4 iters
    int idx = t + k*TPB;
    float2 y2 = pj2[idx];
    float2 l2 = lw2[idx];
    float h0 = l2.x, h1 = l2.y;
    if (mode != 0){
      float2 dd = hd2[idx];
      h0 = fmaf(dd.x, inv_eps, h0);
      h1 = fmaf(dd.y, inv_eps, h1);
    }
    pair4[idx] = make_float4(y2.x, y2.y,
                             fmaf(-c2*y2.x, y2.x, L2E*h0),
                             fmaf(-c2*y2.y, y2.y, L2E*h1));
  }

  int row0 = rc*RPB + rs;
  f2 a2[4];
  #pragma unroll
  for (int r = 0; r < 4; r++){
    float xi = ri[row0 + 32*r];
    float al = c1 * xi;
    a2[r] = (f2){al, al};
  }
  __syncthreads();

  // ---- pass 1: per-row max over this thread's 256-j chunk, 4 rows ----
  int q0 = jc * SPC;
  f2 m2[4];
  #pragma unroll
  for (int r = 0; r < 4; r++) m2[r] = (f2){-INFINITY, -INFINITY};
  #pragma unroll 2
  for (int q = 0; q < SPC; q += 2){
    float4 A = pair4[q0+q];
    float4 B = pair4[q0+q+1];
    f2 yA = (f2){A.x, A.y}, hA = (f2){A.z, A.w};
    f2 yB = (f2){B.x, B.y}, hB = (f2){B.z, B.w};
    #pragma unroll
    for (int r = 0; r < 4; r++){
      m2[r] = __builtin_elementwise_max(m2[r], __builtin_elementwise_fma(a2[r], yA, hA));
      m2[r] = __builtin_elementwise_max(m2[r], __builtin_elementwise_fma(a2[r], yB, hB));
    }
  }
  #pragma unroll
  for (int r = 0; r < 4; r++) pm[jc][rs + 32*r] = fmaxf(m2[r].x, m2[r].y);
  __syncthreads();

  // cooperative combine of per-chunk maxes (one row per thread for t<128)
  if (t < RPB){
    float m = -INFINITY;
    #pragma unroll
    for (int k = 0; k < JSPLIT; k++) m = fmaxf(m, pm[k][t]);
    mmx[t] = m;
  }
  __syncthreads();

  f2 mb[4];
  #pragma unroll
  for (int r = 0; r < 4; r++){
    float m = mmx[rs + 32*r];
    mb[r] = (f2){m, m};
  }

  // ---- pass 2: sum of exp2 with combined max ----
  f2 s2[4];
  #pragma unroll
  for (int r = 0; r < 4; r++) s2[r] = (f2){0.f, 0.f};
  #pragma unroll 2
  for (int q = 0; q < SPC; q += 2){
    float4 A = pair4[q0+q];
    float4 B = pair4[q0+q+1];
    f2 yA = (f2){A.x, A.y}, hA = (f2){A.z, A.w};
    f2 yB = (f2){B.x, B.y}, hB = (f2){B.z, B.w};
    #pragma unroll
    for (int r = 0; r < 4; r++){
      f2 vA = __builtin_elementwise_fma(a2[r], yA, hA) - mb[r];
      f2 vB = __builtin_elementwise_fma(a2[r], yB, hB) - mb[r];
      s2[r] += (f2){__builtin_amdgcn_exp2f(vA.x), __builtin_amdgcn_exp2f(vA.y)};
      s2[r] += (f2){__builtin_amdgcn_exp2f(vB.x), __builtin_amdgcn_exp2f(vB.y)};
    }
  }
  #pragma unroll
  for (int r = 0; r < 4; r++) ps[jc][rs + 32*r] = s2[r].x + s2[r].y;
  __syncthreads();

  if (t < RPB){
    int row = rc*RPB + t;
    float s = 0.f;
    #pragma unroll
    for (int k = 0; k < JSPLIT; k++) s += ps[k][t];
    float m  = mmx[t];
    float xi = ri[row];
    float beta = c2 * xi * xi;
    float lse2 = (m + __builtin_amdgcn_logf(s)) - beta;   // log2-domain LSE
    float tn = -eps * (LN2 * lse2);
    float outv;
    if (mode == 1 || (mode == 2 && mat >= 2)) outv = 0.5f * (dmp[row] + tn);
    else                                      outv = tn;
    op[row] = outv;
  }
}

__global__ void reduce_kernel(const float* __restrict__ dual, const float* __restrict__ logw,
                              const float* __restrict__ counts, float* __restrict__ out){
  int d = blockIdx.x;
  int t = threadIdx.x;
  int lane = t & 63, wave = t >> 6;
  float acc = 0.f;
  for (int k = 0; k < BN/256; k++){
    int i = t + k*256;
    float w  = expf(logw[d*BN + i]);   // exp(-1e9) -> 0, else 1/n
    float fv = dual[0*DN*BN + d*BN + i];
    float gv = dual[1*DN*BN + d*BN + i];
    float av = dual[2*DN*BN + d*BN + i];
    float bv = dual[3*DN*BN + d*BN + i];
    acc += w * ((fv - av) + (gv - bv));
  }
  __shared__ float sh[4];
  float aw = wave_reduce_sum(acc);
  if (lane == 0) sh[wave] = aw;
  __syncthreads();
  if (t == 0){
    float tot = sh[0] + sh[1] + sh[2] + sh[3];
    out[1 + d] = (counts[d] > 1.5f) ? tot : 0.f;
  }
}

__global__ void total_kernel(float* __restrict__ out){
  if (threadIdx.x == 0 && blockIdx.x == 0){
    float s = 0.f;
    for (int d = 0; d < DN; d++) s += out[1 + d];
    out[0] = s / (float)DN;
  }
}

extern "C" void kernel_launch(void* const* d_in, const int* in_sizes, int n_in,
                              void* d_out, int out_size, void* d_ws, size_t ws_size,
                              hipStream_t stream){
  const float* pred = (const float*)d_in[0];
  const float* targ = (const float*)d_in[1];
  float* out = (float*)d_out;
  float* ws  = (float*)d_ws;

  float* xcol   = ws;
  float* ycol   = ws + (size_t)DN*BN;
  float* logw   = ws + (size_t)2*DN*BN;
  float* counts = ws + (size_t)3*DN*BN;
  float* buf0   = ws + (size_t)3*DN*BN + 64;
  float* buf1   = buf0 + (size_t)4*DN*BN;

  // eps schedule (matches geomloss: diameter^p -> blur^p geometric, ratio scaling^p)
  float eps_list[64]; int n = 0;
  {
    const double P = 2.0, DIAM = 8.0, BLUR = 0.05, SC = 0.9;
    double ls = P*log(DIAM), le = P*log(BLUR), st = P*log(SC);
    eps_list[n++] = (float)pow(DIAM, P);                 // 64
    int cnt = (int)ceil((le - ls)/st);                   // 49
    for (int k = 0; k < cnt; k++) eps_list[n++] = (float)exp(ls + st*(double)k);
    eps_list[n++] = (float)(BLUR*BLUR);                  // 0.0025
  }

  setup_kernel<<<DN, 256, 0, stream>>>(pred, targ, xcol, ycol, logw, counts);

  dim3 grid(DN*4*16), blk(TPB);
  float* cur = buf0; float* nxt = buf1;
  {
    float e = eps_list[0];
    sink_step<<<grid, blk, 0, stream>>>(xcol, ycol, logw, cur, cur, e, 1.f/e, 0);
  }
  for (int k = 0; k < n; k++){
    float e = eps_list[k];
    sink_step<<<grid, blk, 0, stream>>>(xcol, ycol, logw, cur, nxt, e, 1.f/e, 1);
    float* tmp = cur; cur = nxt; nxt = tmp;
  }
  {
    float e = eps_list[n-1];
    sink_step<<<grid, blk, 0, stream>>>(xcol, ycol, logw, cur, nxt, e, 1.f/e, 2);
    float* tmp = cur; cur = nxt; nxt = tmp;
  }
  reduce_kernel<<<DN, 256, 0, stream>>>(cur, logw, counts, out);
  total_kernel<<<1, 64, 0, stream>>>(out);
}

// Round 7
// 1142.439 us; speedup vs baseline: 7.2470x; 1.0478x over previous
//
#include <hip/hip_runtime.h>
#include <math.h>

#define BN 2048
#define DN 8
#define NEGW -1e9f
#define TPB 256          // threads per block (4 waves)
#define RPB 128          // rows per block (each thread owns 4 rows)
#define RS 32            // row-slots (t & 31); rows rs, rs+32, rs+64, rs+96
#define JSPLIT 8         // j-chunks; jc = t>>5 (half-wave uniform -> 2-way LDS broadcast, free)
#define SLOTS (BN/2)     // float4 slots (2 j per slot)
#define SPC (SLOTS/JSPLIT) // 128 slots = 256 j per chunk

typedef float f2 __attribute__((ext_vector_type(2)));

static __device__ __forceinline__ float wave_reduce_sum(float v){
  #pragma unroll
  for (int off = 32; off > 0; off >>= 1) v += __shfl_xor(v, off, 64);
  return v;
}

// Transpose inputs into per-dim columns, build masked y, counts, logw.
__global__ void setup_kernel(const float* __restrict__ pred, const float* __restrict__ targ,
                             float* __restrict__ xcol, float* __restrict__ ycol,
                             float* __restrict__ logw, float* __restrict__ counts){
  int d = blockIdx.x;          // 8 blocks
  int t = threadIdx.x;         // 256 threads
  int lane = t & 63, wave = t >> 6;
  float mk[BN/256];
  float c = 0.f;
  for (int k = 0; k < BN/256; k++){
    int i = t + k*256;
    float tv = targ[i*DN + d];
    bool m = !(tv != tv);      // !isnan
    mk[k] = m ? 1.f : 0.f;
    c += mk[k];
    ycol[d*BN + i] = m ? tv : 0.f;
    xcol[d*BN + i] = pred[i*DN + d];
  }
  __shared__ float sh[4];
  __shared__ float logn_sh;
  float cw = wave_reduce_sum(c);
  if (lane == 0) sh[wave] = cw;
  __syncthreads();
  if (t == 0){
    float tot = sh[0] + sh[1] + sh[2] + sh[3];
    counts[d] = tot;
    logn_sh = logf(fmaxf(tot, 1.f));
  }
  __syncthreads();
  float ln = logn_sh;
  for (int k = 0; k < BN/256; k++){
    int i = t + k*256;
    logw[d*BN + i] = (mk[k] > 0.f) ? -ln : NEGW;
  }
}

// One Sinkhorn phase. Round-7: same decomposition as round 6 (4 rows/thread,
// pk math, planar LDS) but the inner loops issue 8 ds_read_b128 back-to-back
// before consuming. Round-6 post-mortem: at 2 waves/SIMD with 2-deep reads,
// LDS service (10.2us/CU) and VALU (11.1us/SIMD) SERIALIZED (sum=21.3 matched
// the measured 20.5). 8-deep batches put ~96cy of LDS service in flight under
// ~128cy of pk-VALU -> pipes overlap.
__global__ __launch_bounds__(TPB) void sink_step(
      const float* __restrict__ xcol, const float* __restrict__ ycol,
      const float* __restrict__ logw,
      const float* __restrict__ dold, float* __restrict__ dnew,
      float eps, float inv_eps, int mode){
  const float L2E = 1.44269504088896340736f;
  const float LN2 = 0.69314718055994530942f;
  __shared__ float4 pair4[SLOTS];         // 16 KB planar: (y0,y1,h2_0,h2_1)
  __shared__ float pm[JSPLIT][RPB];       // 4 KB partial max
  __shared__ float ps[JSPLIT][RPB];       // 4 KB partial sum
  __shared__ float mmx[RPB];              // combined max per row

  int bid = blockIdx.x;
  int rc  = bid & 15;          // 16 row-chunks of 128 rows
  int mat = (bid >> 4) & 3;    // 0:f 1:g 2:a 3:b
  int d   = bid >> 6;          // dim
  int t   = threadIdx.x;
  int rs  = t & (RS-1);        // row-slot
  int jc  = t >> 5;            // j-chunk 0..7

  const float* xb = xcol + d*BN;
  const float* yb = ycol + d*BN;
  const float* lw = logw + d*BN;
  const float* ri; const float* pj; int hsel;
  switch (mat){
    case 0:  ri = xb; pj = yb; hsel = 1; break;  // ft: rows x, pts y, dual g
    case 1:  ri = yb; pj = xb; hsel = 0; break;  // gt: rows y, pts x, dual f
    case 2:  ri = xb; pj = xb; hsel = 2; break;  // at
    default: ri = yb; pj = yb; hsel = 3; break;  // bt
  }
  const float* hd  = dold + (size_t)hsel*DN*BN + d*BN;
  const float* dmp = dold + (size_t)mat *DN*BN + d*BN;
  float*       op  = dnew + (size_t)mat *DN*BN + d*BN;

  const float c1 = L2E * inv_eps;          // log2-domain 1/eps
  const float c2 = 0.5f * inv_eps * L2E;   // log2-domain 1/(2 eps)

  // ---- stage (y,y,h2,h2) planar for all 2048 j into LDS ----
  const float2* pj2 = (const float2*)pj;
  const float2* lw2 = (const float2*)lw;
  const float2* hd2 = (const float2*)hd;
  #pragma unroll
  for (int k = 0; k < SLOTS/TPB; k++){     // 4 iters
    int idx = t + k*TPB;
    float2 y2 = pj2[idx];
    float2 l2 = lw2[idx];
    float h0 = l2.x, h1 = l2.y;
    if (mode != 0){
      float2 dd = hd2[idx];
      h0 = fmaf(dd.x, inv_eps, h0);
      h1 = fmaf(dd.y, inv_eps, h1);
    }
    pair4[idx] = make_float4(y2.x, y2.y,
                             fmaf(-c2*y2.x, y2.x, L2E*h0),
                             fmaf(-c2*y2.y, y2.y, L2E*h1));
  }

  int row0 = rc*RPB + rs;
  f2 a2[4];
  #pragma unroll
  for (int r = 0; r < 4; r++){
    float xi = ri[row0 + 32*r];
    float al = c1 * xi;
    a2[r] = (f2){al, al};
  }
  __syncthreads();

  // ---- pass 1: per-row max, 8-slot read batches ----
  int q0 = jc * SPC;
  f2 m2[4];
  #pragma unroll
  for (int r = 0; r < 4; r++) m2[r] = (f2){-INFINITY, -INFINITY};
  #pragma unroll 1
  for (int q = 0; q < SPC; q += 8){
    float4 P0 = pair4[q0+q+0]; float4 P1 = pair4[q0+q+1];
    float4 P2 = pair4[q0+q+2]; float4 P3 = pair4[q0+q+3];
    float4 P4 = pair4[q0+q+4]; float4 P5 = pair4[q0+q+5];
    float4 P6 = pair4[q0+q+6]; float4 P7 = pair4[q0+q+7];
    #pragma unroll
    for (int r = 0; r < 4; r++){
      f2 a = a2[r], mm = m2[r];
      mm = __builtin_elementwise_max(mm, __builtin_elementwise_fma(a, (f2){P0.x,P0.y}, (f2){P0.z,P0.w}));
      mm = __builtin_elementwise_max(mm, __builtin_elementwise_fma(a, (f2){P1.x,P1.y}, (f2){P1.z,P1.w}));
      mm = __builtin_elementwise_max(mm, __builtin_elementwise_fma(a, (f2){P2.x,P2.y}, (f2){P2.z,P2.w}));
      mm = __builtin_elementwise_max(mm, __builtin_elementwise_fma(a, (f2){P3.x,P3.y}, (f2){P3.z,P3.w}));
      mm = __builtin_elementwise_max(mm, __builtin_elementwise_fma(a, (f2){P4.x,P4.y}, (f2){P4.z,P4.w}));
      mm = __builtin_elementwise_max(mm, __builtin_elementwise_fma(a, (f2){P5.x,P5.y}, (f2){P5.z,P5.w}));
      mm = __builtin_elementwise_max(mm, __builtin_elementwise_fma(a, (f2){P6.x,P6.y}, (f2){P6.z,P6.w}));
      mm = __builtin_elementwise_max(mm, __builtin_elementwise_fma(a, (f2){P7.x,P7.y}, (f2){P7.z,P7.w}));
      m2[r] = mm;
    }
  }
  #pragma unroll
  for (int r = 0; r < 4; r++) pm[jc][rs + 32*r] = fmaxf(m2[r].x, m2[r].y);
  __syncthreads();

  // cooperative combine of per-chunk maxes (one row per thread for t<128)
  if (t < RPB){
    float m = -INFINITY;
    #pragma unroll
    for (int k = 0; k < JSPLIT; k++) m = fmaxf(m, pm[k][t]);
    mmx[t] = m;
  }
  __syncthreads();

  f2 mb[4];
  #pragma unroll
  for (int r = 0; r < 4; r++){
    float m = mmx[rs + 32*r];
    mb[r] = (f2){m, m};
  }

  // ---- pass 2: sum of exp2 with combined max, 8-slot read batches ----
  f2 s2[4];
  #pragma unroll
  for (int r = 0; r < 4; r++) s2[r] = (f2){0.f, 0.f};
  #pragma unroll 1
  for (int q = 0; q < SPC; q += 8){
    float4 P0 = pair4[q0+q+0]; float4 P1 = pair4[q0+q+1];
    float4 P2 = pair4[q0+q+2]; float4 P3 = pair4[q0+q+3];
    float4 P4 = pair4[q0+q+4]; float4 P5 = pair4[q0+q+5];
    float4 P6 = pair4[q0+q+6]; float4 P7 = pair4[q0+q+7];
    #pragma unroll
    for (int r = 0; r < 4; r++){
      f2 a = a2[r], m = mb[r], ss = s2[r];
      f2 v;
      v = __builtin_elementwise_fma(a, (f2){P0.x,P0.y}, (f2){P0.z,P0.w}) - m;
      ss += (f2){__builtin_amdgcn_exp2f(v.x), __builtin_amdgcn_exp2f(v.y)};
      v = __builtin_elementwise_fma(a, (f2){P1.x,P1.y}, (f2){P1.z,P1.w}) - m;
      ss += (f2){__builtin_amdgcn_exp2f(v.x), __builtin_amdgcn_exp2f(v.y)};
      v = __builtin_elementwise_fma(a, (f2){P2.x,P2.y}, (f2){P2.z,P2.w}) - m;
      ss += (f2){__builtin_amdgcn_exp2f(v.x), __builtin_amdgcn_exp2f(v.y)};
      v = __builtin_elementwise_fma(a, (f2){P3.x,P3.y}, (f2){P3.z,P3.w}) - m;
      ss += (f2){__builtin_amdgcn_exp2f(v.x), __builtin_amdgcn_exp2f(v.y)};
      v = __builtin_elementwise_fma(a, (f2){P4.x,P4.y}, (f2){P4.z,P4.w}) - m;
      ss += (f2){__builtin_amdgcn_exp2f(v.x), __builtin_amdgcn_exp2f(v.y)};
      v = __builtin_elementwise_fma(a, (f2){P5.x,P5.y}, (f2){P5.z,P5.w}) - m;
      ss += (f2){__builtin_amdgcn_exp2f(v.x), __builtin_amdgcn_exp2f(v.y)};
      v = __builtin_elementwise_fma(a, (f2){P6.x,P6.y}, (f2){P6.z,P6.w}) - m;
      ss += (f2){__builtin_amdgcn_exp2f(v.x), __builtin_amdgcn_exp2f(v.y)};
      v = __builtin_elementwise_fma(a, (f2){P7.x,P7.y}, (f2){P7.z,P7.w}) - m;
      ss += (f2){__builtin_amdgcn_exp2f(v.x), __builtin_amdgcn_exp2f(v.y)};
      s2[r] = ss;
    }
  }
  #pragma unroll
  for (int r = 0; r < 4; r++) ps[jc][rs + 32*r] = s2[r].x + s2[r].y;
  __syncthreads();

  if (t < RPB){
    int row = rc*RPB + t;
    float s = 0.f;
    #pragma unroll
    for (int k = 0; k < JSPLIT; k++) s += ps[k][t];
    float m  = mmx[t];
    float xi = ri[row];
    float beta = c2 * xi * xi;
    float lse2 = (m + __builtin_amdgcn_logf(s)) - beta;   // log2-domain LSE
    float tn = -eps * (LN2 * lse2);
    float outv;
    if (mode == 1 || (mode == 2 && mat >= 2)) outv = 0.5f * (dmp[row] + tn);
    else                                      outv = tn;
    op[row] = outv;
  }
}

__global__ void reduce_kernel(const float* __restrict__ dual, const float* __restrict__ logw,
                              const float* __restrict__ counts, float* __restrict__ out){
  int d = blockIdx.x;
  int t = threadIdx.x;
  int lane = t & 63, wave = t >> 6;
  float acc = 0.f;
  for (int k = 0; k < BN/256; k++){
    int i = t + k*256;
    float w  = expf(logw[d*BN + i]);   // exp(-1e9) -> 0, else 1/n
    float fv = dual[0*DN*BN + d*BN + i];
    float gv = dual[1*DN*BN + d*BN + i];
    float av = dual[2*DN*BN + d*BN + i];
    float bv = dual[3*DN*BN + d*BN + i];
    acc += w * ((fv - av) + (gv - bv));
  }
  __shared__ float sh[4];
  float aw = wave_reduce_sum(acc);
  if (lane == 0) sh[wave] = aw;
  __syncthreads();
  if (t == 0){
    float tot = sh[0] + sh[1] + sh[2] + sh[3];
    out[1 + d] = (counts[d] > 1.5f) ? tot : 0.f;
  }
}

__global__ void total_kernel(float* __restrict__ out){
  if (threadIdx.x == 0 && blockIdx.x == 0){
    float s = 0.f;
    for (int d = 0; d < DN; d++) s += out[1 + d];
    out[0] = s / (float)DN;
  }
}

extern "C" void kernel_launch(void* const* d_in, const int* in_sizes, int n_in,
                              void* d_out, int out_size, void* d_ws, size_t ws_size,
                              hipStream_t stream){
  const float* pred = (const float*)d_in[0];
  const float* targ = (const float*)d_in[1];
  float* out = (float*)d_out;
  float* ws  = (float*)d_ws;

  float* xcol   = ws;
  float* ycol   = ws + (size_t)DN*BN;
  float* logw   = ws + (size_t)2*DN*BN;
  float* counts = ws + (size_t)3*DN*BN;
  float* buf0   = ws + (size_t)3*DN*BN + 64;
  float* buf1   = buf0 + (size_t)4*DN*BN;

  // eps schedule (matches geomloss: diameter^p -> blur^p geometric, ratio scaling^p)
  float eps_list[64]; int n = 0;
  {
    const double P = 2.0, DIAM = 8.0, BLUR = 0.05, SC = 0.9;
    double ls = P*log(DIAM), le = P*log(BLUR), st = P*log(SC);
    eps_list[n++] = (float)pow(DIAM, P);                 // 64
    int cnt = (int)ceil((le - ls)/st);                   // 49
    for (int k = 0; k < cnt; k++) eps_list[n++] = (float)exp(ls + st*(double)k);
    eps_list[n++] = (float)(BLUR*BLUR);                  // 0.0025
  }

  setup_kernel<<<DN, 256, 0, stream>>>(pred, targ, xcol, ycol, logw, counts);

  dim3 grid(DN*4*16), blk(TPB);
  float* cur = buf0; float* nxt = buf1;
  {
    float e = eps_list[0];
    sink_step<<<grid, blk, 0, stream>>>(xcol, ycol, logw, cur, cur, e, 1.f/e, 0);
  }
  for (int k = 0; k < n; k++){
    float e = eps_list[k];
    sink_step<<<grid, blk, 0, stream>>>(xcol, ycol, logw, cur, nxt, e, 1.f/e, 1);
    float* tmp = cur; cur = nxt; nxt = tmp;
  }
  {
    float e = eps_list[n-1];
    sink_step<<<grid, blk, 0, stream>>>(xcol, ycol, logw, cur, nxt, e, 1.f/e, 2);
    float* tmp = cur; cur = nxt; nxt = tmp;
  }
  reduce_kernel<<<DN, 256, 0, stream>>>(cur, logw, counts, out);
  total_kernel<<<1, 64, 0, stream>>>(out);
}

// Round 8
// 1130.351 us; speedup vs baseline: 7.3245x; 1.0107x over previous
//
#include <hip/hip_runtime.h>
#include <math.h>

#define BN 2048
#define DN 8
#define NEGW -1e9f
#define TPB 256            // threads per block (4 waves)
#define RPB 64             // rows per block (each thread owns 4 rows)
#define RS 16              // row-slots (t & 15); rows rs, rs+16, rs+32, rs+48
#define JSPLIT 16          // j-chunks; jc = t>>4 (quarter-wave uniform broadcast)
#define SLOTS (BN/2)       // logical float4 slots (2 j per slot)
#define SPC (SLOTS/JSPLIT) // 64 slots = 128 j per chunk
#define CPAD 65            // physical chunk stride in slots (+1 pad -> banks differ per jc)

typedef float f2 __attribute__((ext_vector_type(2)));

static __device__ __forceinline__ float wave_reduce_sum(float v){
  #pragma unroll
  for (int off = 32; off > 0; off >>= 1) v += __shfl_xor(v, off, 64);
  return v;
}

// Transpose inputs into per-dim columns, build masked y, counts, logw.
__global__ void setup_kernel(const float* __restrict__ pred, const float* __restrict__ targ,
                             float* __restrict__ xcol, float* __restrict__ ycol,
                             float* __restrict__ logw, float* __restrict__ counts){
  int d = blockIdx.x;          // 8 blocks
  int t = threadIdx.x;         // 256 threads
  int lane = t & 63, wave = t >> 6;
  float mk[BN/256];
  float c = 0.f;
  for (int k = 0; k < BN/256; k++){
    int i = t + k*256;
    float tv = targ[i*DN + d];
    bool m = !(tv != tv);      // !isnan
    mk[k] = m ? 1.f : 0.f;
    c += mk[k];
    ycol[d*BN + i] = m ? tv : 0.f;
    xcol[d*BN + i] = pred[i*DN + d];
  }
  __shared__ float sh[4];
  __shared__ float logn_sh;
  float cw = wave_reduce_sum(c);
  if (lane == 0) sh[wave] = cw;
  __syncthreads();
  if (t == 0){
    float tot = sh[0] + sh[1] + sh[2] + sh[3];
    counts[d] = tot;
    logn_sh = logf(fmaxf(tot, 1.f));
  }
  __syncthreads();
  float ln = logn_sh;
  for (int k = 0; k < BN/256; k++){
    int i = t + k*256;
    logw[d*BN + i] = (mk[k] > 0.f) ? -ln : NEGW;
  }
}

// One Sinkhorn phase. Round-8: same per-CU instruction budget as round 7
// (4 rows/thread, pk math, 8-deep read batches) but 64 rows/block ->
// grid 1024 = 4 blocks/CU = 4 waves/SIMD. Rounds 5-7 post-mortem: all
// structures landed ~19-21us = 1.7x the issue model at 2 waves/SIMD ->
// issue-stall-bound, not pipe-bound; doubling resident waves covers stalls.
// Chunk bases padded (phys slot = s + s/64) so the 4 distinct broadcast
// addresses per wave-read hit different banks.
__global__ __launch_bounds__(TPB) void sink_step(
      const float* __restrict__ xcol, const float* __restrict__ ycol,
      const float* __restrict__ logw,
      const float* __restrict__ dold, float* __restrict__ dnew,
      float eps, float inv_eps, int mode){
  const float L2E = 1.44269504088896340736f;
  const float LN2 = 0.69314718055994530942f;
  __shared__ float4 pair4[JSPLIT*CPAD];   // ~16.25 KB planar: (y0,y1,h2_0,h2_1)
  __shared__ float pm[JSPLIT][RPB];       // 4 KB partial max
  __shared__ float ps[JSPLIT][RPB];       // 4 KB partial sum
  __shared__ float mmx[RPB];              // combined max per row

  int bid = blockIdx.x;
  int rc  = bid & 31;          // 32 row-chunks of 64 rows
  int mat = (bid >> 5) & 3;    // 0:f 1:g 2:a 3:b
  int d   = bid >> 7;          // dim
  int t   = threadIdx.x;
  int rs  = t & (RS-1);        // row-slot
  int jc  = t >> 4;            // j-chunk 0..15

  const float* xb = xcol + d*BN;
  const float* yb = ycol + d*BN;
  const float* lw = logw + d*BN;
  const float* ri; const float* pj; int hsel;
  switch (mat){
    case 0:  ri = xb; pj = yb; hsel = 1; break;  // ft: rows x, pts y, dual g
    case 1:  ri = yb; pj = xb; hsel = 0; break;  // gt: rows y, pts x, dual f
    case 2:  ri = xb; pj = xb; hsel = 2; break;  // at
    default: ri = yb; pj = yb; hsel = 3; break;  // bt
  }
  const float* hd  = dold + (size_t)hsel*DN*BN + d*BN;
  const float* dmp = dold + (size_t)mat *DN*BN + d*BN;
  float*       op  = dnew + (size_t)mat *DN*BN + d*BN;

  const float c1 = L2E * inv_eps;          // log2-domain 1/eps
  const float c2 = 0.5f * inv_eps * L2E;   // log2-domain 1/(2 eps)

  // ---- stage (y,y,h2,h2) planar for all 2048 j into LDS (padded chunks) ----
  const float2* pj2 = (const float2*)pj;
  const float2* lw2 = (const float2*)lw;
  const float2* hd2 = (const float2*)hd;
  #pragma unroll
  for (int k = 0; k < SLOTS/TPB; k++){     // 4 iters
    int idx = t + k*TPB;
    int phys = idx + (idx >> 6);           // +1 pad slot per 64
    float2 y2 = pj2[idx];
    float2 l2 = lw2[idx];
    float h0 = l2.x, h1 = l2.y;
    if (mode != 0){
      float2 dd = hd2[idx];
      h0 = fmaf(dd.x, inv_eps, h0);
      h1 = fmaf(dd.y, inv_eps, h1);
    }
    pair4[phys] = make_float4(y2.x, y2.y,
                              fmaf(-c2*y2.x, y2.x, L2E*h0),
                              fmaf(-c2*y2.y, y2.y, L2E*h1));
  }

  int row0 = rc*RPB + rs;
  f2 a2[4];
  #pragma unroll
  for (int r = 0; r < 4; r++){
    float xi = ri[row0 + RS*r];
    float al = c1 * xi;
    a2[r] = (f2){al, al};
  }
  __syncthreads();

  // ---- pass 1: per-row max, 8-slot read batches ----
  const float4* cb = pair4 + jc*CPAD;      // this chunk's base
  f2 m2[4];
  #pragma unroll
  for (int r = 0; r < 4; r++) m2[r] = (f2){-INFINITY, -INFINITY};
  #pragma unroll 1
  for (int q = 0; q < SPC; q += 8){
    float4 P0 = cb[q+0]; float4 P1 = cb[q+1];
    float4 P2 = cb[q+2]; float4 P3 = cb[q+3];
    float4 P4 = cb[q+4]; float4 P5 = cb[q+5];
    float4 P6 = cb[q+6]; float4 P7 = cb[q+7];
    #pragma unroll
    for (int r = 0; r < 4; r++){
      f2 a = a2[r], mm = m2[r];
      mm = __builtin_elementwise_max(mm, __builtin_elementwise_fma(a, (f2){P0.x,P0.y}, (f2){P0.z,P0.w}));
      mm = __builtin_elementwise_max(mm, __builtin_elementwise_fma(a, (f2){P1.x,P1.y}, (f2){P1.z,P1.w}));
      mm = __builtin_elementwise_max(mm, __builtin_elementwise_fma(a, (f2){P2.x,P2.y}, (f2){P2.z,P2.w}));
      mm = __builtin_elementwise_max(mm, __builtin_elementwise_fma(a, (f2){P3.x,P3.y}, (f2){P3.z,P3.w}));
      mm = __builtin_elementwise_max(mm, __builtin_elementwise_fma(a, (f2){P4.x,P4.y}, (f2){P4.z,P4.w}));
      mm = __builtin_elementwise_max(mm, __builtin_elementwise_fma(a, (f2){P5.x,P5.y}, (f2){P5.z,P5.w}));
      mm = __builtin_elementwise_max(mm, __builtin_elementwise_fma(a, (f2){P6.x,P6.y}, (f2){P6.z,P6.w}));
      mm = __builtin_elementwise_max(mm, __builtin_elementwise_fma(a, (f2){P7.x,P7.y}, (f2){P7.z,P7.w}));
      m2[r] = mm;
    }
  }
  #pragma unroll
  for (int r = 0; r < 4; r++) pm[jc][rs + RS*r] = fmaxf(m2[r].x, m2[r].y);
  __syncthreads();

  // cooperative combine of per-chunk maxes (one row per thread for t<64)
  if (t < RPB){
    float m = -INFINITY;
    #pragma unroll
    for (int k = 0; k < JSPLIT; k++) m = fmaxf(m, pm[k][t]);
    mmx[t] = m;
  }
  __syncthreads();

  f2 mb[4];
  #pragma unroll
  for (int r = 0; r < 4; r++){
    float m = mmx[rs + RS*r];
    mb[r] = (f2){m, m};
  }

  // ---- pass 2: sum of exp2 with combined max, 8-slot read batches ----
  f2 s2[4];
  #pragma unroll
  for (int r = 0; r < 4; r++) s2[r] = (f2){0.f, 0.f};
  #pragma unroll 1
  for (int q = 0; q < SPC; q += 8){
    float4 P0 = cb[q+0]; float4 P1 = cb[q+1];
    float4 P2 = cb[q+2]; float4 P3 = cb[q+3];
    float4 P4 = cb[q+4]; float4 P5 = cb[q+5];
    float4 P6 = cb[q+6]; float4 P7 = cb[q+7];
    #pragma unroll
    for (int r = 0; r < 4; r++){
      f2 a = a2[r], m = mb[r], ss = s2[r];
      f2 v;
      v = __builtin_elementwise_fma(a, (f2){P0.x,P0.y}, (f2){P0.z,P0.w}) - m;
      ss += (f2){__builtin_amdgcn_exp2f(v.x), __builtin_amdgcn_exp2f(v.y)};
      v = __builtin_elementwise_fma(a, (f2){P1.x,P1.y}, (f2){P1.z,P1.w}) - m;
      ss += (f2){__builtin_amdgcn_exp2f(v.x), __builtin_amdgcn_exp2f(v.y)};
      v = __builtin_elementwise_fma(a, (f2){P2.x,P2.y}, (f2){P2.z,P2.w}) - m;
      ss += (f2){__builtin_amdgcn_exp2f(v.x), __builtin_amdgcn_exp2f(v.y)};
      v = __builtin_elementwise_fma(a, (f2){P3.x,P3.y}, (f2){P3.z,P3.w}) - m;
      ss += (f2){__builtin_amdgcn_exp2f(v.x), __builtin_amdgcn_exp2f(v.y)};
      v = __builtin_elementwise_fma(a, (f2){P4.x,P4.y}, (f2){P4.z,P4.w}) - m;
      ss += (f2){__builtin_amdgcn_exp2f(v.x), __builtin_amdgcn_exp2f(v.y)};
      v = __builtin_elementwise_fma(a, (f2){P5.x,P5.y}, (f2){P5.z,P5.w}) - m;
      ss += (f2){__builtin_amdgcn_exp2f(v.x), __builtin_amdgcn_exp2f(v.y)};
      v = __builtin_elementwise_fma(a, (f2){P6.x,P6.y}, (f2){P6.z,P6.w}) - m;
      ss += (f2){__builtin_amdgcn_exp2f(v.x), __builtin_amdgcn_exp2f(v.y)};
      v = __builtin_elementwise_fma(a, (f2){P7.x,P7.y}, (f2){P7.z,P7.w}) - m;
      ss += (f2){__builtin_amdgcn_exp2f(v.x), __builtin_amdgcn_exp2f(v.y)};
      s2[r] = ss;
    }
  }
  #pragma unroll
  for (int r = 0; r < 4; r++) ps[jc][rs + RS*r] = s2[r].x + s2[r].y;
  __syncthreads();

  if (t < RPB){
    int row = rc*RPB + t;
    float s = 0.f;
    #pragma unroll
    for (int k = 0; k < JSPLIT; k++) s += ps[k][t];
    float m  = mmx[t];
    float xi = ri[row];
    float beta = c2 * xi * xi;
    float lse2 = (m + __builtin_amdgcn_logf(s)) - beta;   // log2-domain LSE
    float tn = -eps * (LN2 * lse2);
    float outv;
    if (mode == 1 || (mode == 2 && mat >= 2)) outv = 0.5f * (dmp[row] + tn);
    else                                      outv = tn;
    op[row] = outv;
  }
}

__global__ void reduce_kernel(const float* __restrict__ dual, const float* __restrict__ logw,
                              const float* __restrict__ counts, float* __restrict__ out){
  int d = blockIdx.x;
  int t = threadIdx.x;
  int lane = t & 63, wave = t >> 6;
  float acc = 0.f;
  for (int k = 0; k < BN/256; k++){
    int i = t + k*256;
    float w  = expf(logw[d*BN + i]);   // exp(-1e9) -> 0, else 1/n
    float fv = dual[0*DN*BN + d*BN + i];
    float gv = dual[1*DN*BN + d*BN + i];
    float av = dual[2*DN*BN + d*BN + i];
    float bv = dual[3*DN*BN + d*BN + i];
    acc += w * ((fv - av) + (gv - bv));
  }
  __shared__ float sh[4];
  float aw = wave_reduce_sum(acc);
  if (lane == 0) sh[wave] = aw;
  __syncthreads();
  if (t == 0){
    float tot = sh[0] + sh[1] + sh[2] + sh[3];
    out[1 + d] = (counts[d] > 1.5f) ? tot : 0.f;
  }
}

__global__ void total_kernel(float* __restrict__ out){
  if (threadIdx.x == 0 && blockIdx.x == 0){
    float s = 0.f;
    for (int d = 0; d < DN; d++) s += out[1 + d];
    out[0] = s / (float)DN;
  }
}

extern "C" void kernel_launch(void* const* d_in, const int* in_sizes, int n_in,
                              void* d_out, int out_size, void* d_ws, size_t ws_size,
                              hipStream_t stream){
  const float* pred = (const float*)d_in[0];
  const float* targ = (const float*)d_in[1];
  float* out = (float*)d_out;
  float* ws  = (float*)d_ws;

  float* xcol   = ws;
  float* ycol   = ws + (size_t)DN*BN;
  float* logw   = ws + (size_t)2*DN*BN;
  float* counts = ws + (size_t)3*DN*BN;
  float* buf0   = ws + (size_t)3*DN*BN + 64;
  float* buf1   = buf0 + (size_t)4*DN*BN;

  // eps schedule (matches geomloss: diameter^p -> blur^p geometric, ratio scaling^p)
  float eps_list[64]; int n = 0;
  {
    const double P = 2.0, DIAM = 8.0, BLUR = 0.05, SC = 0.9;
    double ls = P*log(DIAM), le = P*log(BLUR), st = P*log(SC);
    eps_list[n++] = (float)pow(DIAM, P);                 // 64
    int cnt = (int)ceil((le - ls)/st);                   // 49
    for (int k = 0; k < cnt; k++) eps_list[n++] = (float)exp(ls + st*(double)k);
    eps_list[n++] = (float)(BLUR*BLUR);                  // 0.0025
  }

  setup_kernel<<<DN, 256, 0, stream>>>(pred, targ, xcol, ycol, logw, counts);

  dim3 grid(DN*4*32), blk(TPB);
  float* cur = buf0; float* nxt = buf1;
  {
    float e = eps_list[0];
    sink_step<<<grid, blk, 0, stream>>>(xcol, ycol, logw, cur, cur, e, 1.f/e, 0);
  }
  for (int k = 0; k < n; k++){
    float e = eps_list[k];
    sink_step<<<grid, blk, 0, stream>>>(xcol, ycol, logw, cur, nxt, e, 1.f/e, 1);
    float* tmp = cur; cur = nxt; nxt = tmp;
  }
  {
    float e = eps_list[n-1];
    sink_step<<<grid, blk, 0, stream>>>(xcol, ycol, logw, cur, nxt, e, 1.f/e, 2);
    float* tmp = cur; cur = nxt; nxt = tmp;
  }
  reduce_kernel<<<DN, 256, 0, stream>>>(cur, logw, counts, out);
  total_kernel<<<1, 64, 0, stream>>>(out);
}

// Round 9
// 1075.279 us; speedup vs baseline: 7.6997x; 1.0512x over previous
//
#include <hip/hip_runtime.h>
#include <math.h>

#define BN 2048
#define DN 8
#define NEGW -1e9f
#define TPB 256            // threads per block (4 waves)
#define RPB 64             // rows per block (each thread owns 4 rows)
#define RS 16              // row-slots (t & 15); rows rs, rs+16, rs+32, rs+48
#define JSPLIT 16          // j-chunks; jc = t>>4 (quarter-wave uniform broadcast)
#define SLOTS (BN/2)       // logical float4 slots (2 j per slot)
#define SPC (SLOTS/JSPLIT) // 64 slots = 128 j per chunk
#define CPAD 65            // physical chunk stride in slots (+1 pad)

typedef float f2 __attribute__((ext_vector_type(2)));

static __device__ __forceinline__ float wave_reduce_sum(float v){
  #pragma unroll
  for (int off = 32; off > 0; off >>= 1) v += __shfl_xor(v, off, 64);
  return v;
}

// Transpose inputs into per-dim columns, build masked y, counts, logw.
__global__ void setup_kernel(const float* __restrict__ pred, const float* __restrict__ targ,
                             float* __restrict__ xcol, float* __restrict__ ycol,
                             float* __restrict__ logw, float* __restrict__ counts){
  int d = blockIdx.x;          // 8 blocks
  int t = threadIdx.x;         // 256 threads
  int lane = t & 63, wave = t >> 6;
  float mk[BN/256];
  float c = 0.f;
  for (int k = 0; k < BN/256; k++){
    int i = t + k*256;
    float tv = targ[i*DN + d];
    bool m = !(tv != tv);      // !isnan
    mk[k] = m ? 1.f : 0.f;
    c += mk[k];
    ycol[d*BN + i] = m ? tv : 0.f;
    xcol[d*BN + i] = pred[i*DN + d];
  }
  __shared__ float sh[4];
  __shared__ float logn_sh;
  float cw = wave_reduce_sum(c);
  if (lane == 0) sh[wave] = cw;
  __syncthreads();
  if (t == 0){
    float tot = sh[0] + sh[1] + sh[2] + sh[3];
    counts[d] = tot;
    logn_sh = logf(fmaxf(tot, 1.f));
  }
  __syncthreads();
  float ln = logn_sh;
  for (int k = 0; k < BN/256; k++){
    int i = t + k*256;
    logw[d*BN + i] = (mk[k] > 0.f) ? -ln : NEGW;
  }
}

// One Sinkhorn phase. Round-9: SINGLE-SWEEP online softmax. Rounds 5-8
// post-mortem: step time pinned ~19-21us across all occupancy/ILP configs;
// only work-reduction ever moved it (sum-of-pipes model: LDS 10.2 + VALU 4.3
// + trans 6.8 ~= 21 fits r8). This round halves LDS reads (one j-sweep) and
// cuts pass-2's fma recompute via exact online max tracking:
//   per 8-slot batch: v = fma(a,y,h2) once; batch max tree; one rescale
//   ss = ss*2^(m_old-m_new); accumulate exp2(v-m_new) in 2 accumulators.
// Numerically equivalent to two-pass LSE up to ~16 extra roundings/row.
__global__ __launch_bounds__(TPB) void sink_step(
      const float* __restrict__ xcol, const float* __restrict__ ycol,
      const float* __restrict__ logw,
      const float* __restrict__ dold, float* __restrict__ dnew,
      float eps, float inv_eps, int mode){
  const float L2E = 1.44269504088896340736f;
  const float LN2 = 0.69314718055994530942f;
  __shared__ float4 pair4[JSPLIT*CPAD];   // ~16.25 KB planar: (y0,y1,h2_0,h2_1)
  __shared__ float2 pms[JSPLIT][RPB];     // 8 KB: per-chunk (max, sum)

  int bid = blockIdx.x;
  int rc  = bid & 31;          // 32 row-chunks of 64 rows
  int mat = (bid >> 5) & 3;    // 0:f 1:g 2:a 3:b
  int d   = bid >> 7;          // dim
  int t   = threadIdx.x;
  int rs  = t & (RS-1);        // row-slot
  int jc  = t >> 4;            // j-chunk 0..15

  const float* xb = xcol + d*BN;
  const float* yb = ycol + d*BN;
  const float* lw = logw + d*BN;
  const float* ri; const float* pj; int hsel;
  switch (mat){
    case 0:  ri = xb; pj = yb; hsel = 1; break;  // ft: rows x, pts y, dual g
    case 1:  ri = yb; pj = xb; hsel = 0; break;  // gt: rows y, pts x, dual f
    case 2:  ri = xb; pj = xb; hsel = 2; break;  // at
    default: ri = yb; pj = yb; hsel = 3; break;  // bt
  }
  const float* hd  = dold + (size_t)hsel*DN*BN + d*BN;
  const float* dmp = dold + (size_t)mat *DN*BN + d*BN;
  float*       op  = dnew + (size_t)mat *DN*BN + d*BN;

  const float c1 = L2E * inv_eps;          // log2-domain 1/eps
  const float c2 = 0.5f * inv_eps * L2E;   // log2-domain 1/(2 eps)

  // ---- stage (y,y,h2,h2) planar for all 2048 j into LDS (padded chunks) ----
  const float2* pj2 = (const float2*)pj;
  const float2* lw2 = (const float2*)lw;
  const float2* hd2 = (const float2*)hd;
  #pragma unroll
  for (int k = 0; k < SLOTS/TPB; k++){     // 4 iters
    int idx = t + k*TPB;
    int phys = idx + (idx >> 6);           // +1 pad slot per 64
    float2 y2 = pj2[idx];
    float2 l2 = lw2[idx];
    float h0 = l2.x, h1 = l2.y;
    if (mode != 0){
      float2 dd = hd2[idx];
      h0 = fmaf(dd.x, inv_eps, h0);
      h1 = fmaf(dd.y, inv_eps, h1);
    }
    pair4[phys] = make_float4(y2.x, y2.y,
                              fmaf(-c2*y2.x, y2.x, L2E*h0),
                              fmaf(-c2*y2.y, y2.y, L2E*h1));
  }

  int row0 = rc*RPB + rs;
  f2 a2[4];
  #pragma unroll
  for (int r = 0; r < 4; r++){
    float xi = ri[row0 + RS*r];
    float al = c1 * xi;
    a2[r] = (f2){al, al};
  }
  __syncthreads();

  // ---- single sweep: online max + exp-sum, 8-slot read batches ----
  const float4* cb = pair4 + jc*CPAD;      // this chunk's base
  float mrow[4];
  f2 sA[4], sB[4];
  #pragma unroll
  for (int r = 0; r < 4; r++){
    mrow[r] = -INFINITY;
    sA[r] = (f2){0.f, 0.f};
    sB[r] = (f2){0.f, 0.f};
  }
  #pragma unroll 1
  for (int q = 0; q < SPC; q += 8){
    float4 P0 = cb[q+0]; float4 P1 = cb[q+1];
    float4 P2 = cb[q+2]; float4 P3 = cb[q+3];
    float4 P4 = cb[q+4]; float4 P5 = cb[q+5];
    float4 P6 = cb[q+6]; float4 P7 = cb[q+7];
    #pragma unroll
    for (int r = 0; r < 4; r++){
      f2 a = a2[r];
      f2 v0 = __builtin_elementwise_fma(a, (f2){P0.x,P0.y}, (f2){P0.z,P0.w});
      f2 v1 = __builtin_elementwise_fma(a, (f2){P1.x,P1.y}, (f2){P1.z,P1.w});
      f2 v2 = __builtin_elementwise_fma(a, (f2){P2.x,P2.y}, (f2){P2.z,P2.w});
      f2 v3 = __builtin_elementwise_fma(a, (f2){P3.x,P3.y}, (f2){P3.z,P3.w});
      f2 v4 = __builtin_elementwise_fma(a, (f2){P4.x,P4.y}, (f2){P4.z,P4.w});
      f2 v5 = __builtin_elementwise_fma(a, (f2){P5.x,P5.y}, (f2){P5.z,P5.w});
      f2 v6 = __builtin_elementwise_fma(a, (f2){P6.x,P6.y}, (f2){P6.z,P6.w});
      f2 v7 = __builtin_elementwise_fma(a, (f2){P7.x,P7.y}, (f2){P7.z,P7.w});
      // batch max tree
      f2 t0 = __builtin_elementwise_max(v0, v1);
      f2 t1 = __builtin_elementwise_max(v2, v3);
      f2 t2 = __builtin_elementwise_max(v4, v5);
      f2 t3 = __builtin_elementwise_max(v6, v7);
      f2 u0 = __builtin_elementwise_max(t0, t1);
      f2 u1 = __builtin_elementwise_max(t2, t3);
      f2 w  = __builtin_elementwise_max(u0, u1);
      float bm = fmaxf(w.x, w.y);
      float mo = mrow[r];
      float mn = fmaxf(mo, bm);
      float sc = __builtin_amdgcn_exp2f(mo - mn);   // first batch: exp2(-inf)=0
      mrow[r] = mn;
      f2 scv = (f2){sc, sc};
      f2 mv  = (f2){mn, mn};
      f2 e;
      e = v0 - mv;
      f2 x0 = (f2){__builtin_amdgcn_exp2f(e.x), __builtin_amdgcn_exp2f(e.y)};
      e = v1 - mv;
      f2 x1 = (f2){__builtin_amdgcn_exp2f(e.x), __builtin_amdgcn_exp2f(e.y)};
      e = v2 - mv;
      f2 x2 = (f2){__builtin_amdgcn_exp2f(e.x), __builtin_amdgcn_exp2f(e.y)};
      e = v3 - mv;
      f2 x3 = (f2){__builtin_amdgcn_exp2f(e.x), __builtin_amdgcn_exp2f(e.y)};
      e = v4 - mv;
      f2 x4 = (f2){__builtin_amdgcn_exp2f(e.x), __builtin_amdgcn_exp2f(e.y)};
      e = v5 - mv;
      f2 x5 = (f2){__builtin_amdgcn_exp2f(e.x), __builtin_amdgcn_exp2f(e.y)};
      e = v6 - mv;
      f2 x6 = (f2){__builtin_amdgcn_exp2f(e.x), __builtin_amdgcn_exp2f(e.y)};
      e = v7 - mv;
      f2 x7 = (f2){__builtin_amdgcn_exp2f(e.x), __builtin_amdgcn_exp2f(e.y)};
      // two accumulator chains, rescaled once per batch
      sA[r] = __builtin_elementwise_fma(sA[r], scv, x0);
      sB[r] = __builtin_elementwise_fma(sB[r], scv, x1);
      sA[r] += x2;  sB[r] += x3;
      sA[r] += x4;  sB[r] += x5;
      sA[r] += x6;  sB[r] += x7;
    }
  }
  #pragma unroll
  for (int r = 0; r < 4; r++){
    f2 s = sA[r] + sB[r];
    pms[jc][rs + RS*r] = make_float2(mrow[r], s.x + s.y);
  }
  __syncthreads();

  // ---- cross-chunk merge: M = max m_k; s = sum s_k * 2^(m_k - M) ----
  if (t < RPB){
    int row = rc*RPB + t;
    float M = -INFINITY;
    #pragma unroll
    for (int k = 0; k < JSPLIT; k++) M = fmaxf(M, pms[k][t].x);
    float s = 0.f;
    #pragma unroll
    for (int k = 0; k < JSPLIT; k++){
      float2 p = pms[k][t];
      s = fmaf(p.y, __builtin_amdgcn_exp2f(p.x - M), s);
    }
    float xi = ri[row];
    float beta = c2 * xi * xi;
    float lse2 = (M + __builtin_amdgcn_logf(s)) - beta;   // log2-domain LSE
    float tn = -eps * (LN2 * lse2);
    float outv;
    if (mode == 1 || (mode == 2 && mat >= 2)) outv = 0.5f * (dmp[row] + tn);
    else                                      outv = tn;
    op[row] = outv;
  }
}

__global__ void reduce_kernel(const float* __restrict__ dual, const float* __restrict__ logw,
                              const float* __restrict__ counts, float* __restrict__ out){
  int d = blockIdx.x;
  int t = threadIdx.x;
  int lane = t & 63, wave = t >> 6;
  float acc = 0.f;
  for (int k = 0; k < BN/256; k++){
    int i = t + k*256;
    float w  = expf(logw[d*BN + i]);   // exp(-1e9) -> 0, else 1/n
    float fv = dual[0*DN*BN + d*BN + i];
    float gv = dual[1*DN*BN + d*BN + i];
    float av = dual[2*DN*BN + d*BN + i];
    float bv = dual[3*DN*BN + d*BN + i];
    acc += w * ((fv - av) + (gv - bv));
  }
  __shared__ float sh[4];
  float aw = wave_reduce_sum(acc);
  if (lane == 0) sh[wave] = aw;
  __syncthreads();
  if (t == 0){
    float tot = sh[0] + sh[1] + sh[2] + sh[3];
    out[1 + d] = (counts[d] > 1.5f) ? tot : 0.f;
  }
}

__global__ void total_kernel(float* __restrict__ out){
  if (threadIdx.x == 0 && blockIdx.x == 0){
    float s = 0.f;
    for (int d = 0; d < DN; d++) s += out[1 + d];
    out[0] = s / (float)DN;
  }
}

extern "C" void kernel_launch(void* const* d_in, const int* in_sizes, int n_in,
                              void* d_out, int out_size, void* d_ws, size_t ws_size,
                              hipStream_t stream){
  const float* pred = (const float*)d_in[0];
  const float* targ = (const float*)d_in[1];
  float* out = (float*)d_out;
  float* ws  = (float*)d_ws;

  float* xcol   = ws;
  float* ycol   = ws + (size_t)DN*BN;
  float* logw   = ws + (size_t)2*DN*BN;
  float* counts = ws + (size_t)3*DN*BN;
  float* buf0   = ws + (size_t)3*DN*BN + 64;
  float* buf1   = buf0 + (size_t)4*DN*BN;

  // eps schedule (matches geomloss: diameter^p -> blur^p geometric, ratio scaling^p)
  float eps_list[64]; int n = 0;
  {
    const double P = 2.0, DIAM = 8.0, BLUR = 0.05, SC = 0.9;
    double ls = P*log(DIAM), le = P*log(BLUR), st = P*log(SC);
    eps_list[n++] = (float)pow(DIAM, P);                 // 64
    int cnt = (int)ceil((le - ls)/st);                   // 49
    for (int k = 0; k < cnt; k++) eps_list[n++] = (float)exp(ls + st*(double)k);
    eps_list[n++] = (float)(BLUR*BLUR);                  // 0.0025
  }

  setup_kernel<<<DN, 256, 0, stream>>>(pred, targ, xcol, ycol, logw, counts);

  dim3 grid(DN*4*32), blk(TPB);
  float* cur = buf0; float* nxt = buf1;
  {
    float e = eps_list[0];
    sink_step<<<grid, blk, 0, stream>>>(xcol, ycol, logw, cur, cur, e, 1.f/e, 0);
  }
  for (int k = 0; k < n; k++){
    float e = eps_list[k];
    sink_step<<<grid, blk, 0, stream>>>(xcol, ycol, logw, cur, nxt, e, 1.f/e, 1);
    float* tmp = cur; cur = nxt; nxt = tmp;
  }
  {
    float e = eps_list[n-1];
    sink_step<<<grid, blk, 0, stream>>>(xcol, ycol, logw, cur, nxt, e, 1.f/e, 2);
    float* tmp = cur; cur = nxt; nxt = tmp;
  }
  reduce_kernel<<<DN, 256, 0, stream>>>(cur, logw, counts, out);
  total_kernel<<<1, 64, 0, stream>>>(out);
}